// Round 1
// baseline (4876.622 us; speedup 1.0000x reference)
//
#include <hip/hip_runtime.h>
#include <cstdint>

// GIN model: N=100000 nodes, F=64 in, H=128 hidden, C=10 classes, E=1600000 edges.
// Pipeline: agg1 = x + scatter(x) ; h = mlp1(agg1) ; bn1+relu -> hbn (also agg2 init)
//           agg2 += scatter(hbn) ; h2 = mlp2(agg2) ; bn2+relu -> latent ; classifier.
// Round 1: correctness-first. Scatter via f32 atomics; MLPs via register-cached weights.

#define NN 100000
#define FF 64
#define HH 128
#define CC 10
#define EE 1600000
#define BN_EPS 1e-5f

// ---------------- edge dtype detection (int64 vs int32) ----------------
__global__ void detect_kernel(const unsigned int* __restrict__ ei, int* __restrict__ flag) {
    if (threadIdx.x == 0) {
        // int64 little-endian values < 2^31 => every odd 32-bit word is 0
        bool i64 = (ei[1] == 0u) && (ei[3] == 0u) && (ei[5] == 0u) && (ei[7] == 0u);
        *flag = i64 ? 1 : 0;
    }
}

// ---------------- agg1 = x (copy) ----------------
__global__ __launch_bounds__(256) void copy_kernel(const float* __restrict__ src,
                                                   float* __restrict__ dst, int n4) {
    int i = blockIdx.x * 256 + threadIdx.x;
    if (i < n4) ((float4*)dst)[i] = ((const float4*)src)[i];
}

// ---------------- scatter-add: agg[dst] += x[src] ----------------
template <int FDIM>
__global__ __launch_bounds__(256) void scatter_kernel(const void* __restrict__ eiv,
                                                      const float* __restrict__ x,
                                                      float* __restrict__ agg,
                                                      const int* __restrict__ flag) {
    constexpr int CH = FDIM / 4;  // float4 chunks per edge
    long long tid = (long long)blockIdx.x * 256 + threadIdx.x;
    int e = (int)(tid / CH);
    int c = (int)(tid % CH);
    if (e >= EE) return;
    int s, d;
    if (*flag) {
        const long long* ei = (const long long*)eiv;
        s = (int)ei[e];
        d = (int)ei[EE + e];
    } else {
        const int* ei = (const int*)eiv;
        s = ei[e];
        d = ei[EE + e];
    }
    const float4 v = *(const float4*)(x + (long long)s * FDIM + c * 4);
    float* p = agg + (long long)d * FDIM + c * 4;
    atomicAdd(p + 0, v.x);
    atomicAdd(p + 1, v.y);
    atomicAdd(p + 2, v.z);
    atomicAdd(p + 3, v.w);
}

// ---------------- MLP: out = relu(in@wa+ba)@wb+bb, plus BN stats ----------------
// Block 256: col = tid&127, half = tid>>7. Weights register-cached (k split across halves).
template <int KIN>
__global__ __launch_bounds__(256) void mlp_kernel(const float* __restrict__ in,
                                                  const float* __restrict__ wa,
                                                  const float* __restrict__ ba,
                                                  const float* __restrict__ wb,
                                                  const float* __restrict__ bb,
                                                  float* __restrict__ out,
                                                  float* __restrict__ bnsum,
                                                  float* __restrict__ bnsq) {
    constexpr int KH = KIN / 2;
    __shared__ float s_in[KIN];
    __shared__ float s_h1[HH];
    __shared__ float s_part[2][HH];
    const int col = threadIdx.x & 127;
    const int half = threadIdx.x >> 7;

    float wra[KH];
#pragma unroll
    for (int k = 0; k < KH; k++) wra[k] = wa[(half * KH + k) * HH + col];
    float wrb[64];
#pragma unroll
    for (int k = 0; k < 64; k++) wrb[k] = wb[(half * 64 + k) * HH + col];
    const float bav = ba[col], bbv = bb[col];

    float lsum = 0.f, lsq = 0.f;
    for (int row = blockIdx.x; row < NN; row += gridDim.x) {
        if (threadIdx.x < KIN) s_in[threadIdx.x] = in[(long long)row * KIN + threadIdx.x];
        __syncthreads();
        float p = 0.f;
#pragma unroll
        for (int k = 0; k < KH; k++) p = fmaf(s_in[half * KH + k], wra[k], p);
        s_part[half][col] = p;
        __syncthreads();
        if (half == 0) {
            s_h1[col] = fmaxf(s_part[0][col] + s_part[1][col] + bav, 0.f);
        }
        __syncthreads();
        float p2 = 0.f;
#pragma unroll
        for (int k = 0; k < 64; k++) p2 = fmaf(s_h1[half * 64 + k], wrb[k], p2);
        s_part[half][col] = p2;
        __syncthreads();
        if (half == 0) {
            float v = s_part[0][col] + s_part[1][col] + bbv;
            out[(long long)row * HH + col] = v;
            lsum += v;
            lsq += v * v;
        }
        __syncthreads();  // protect s_in/s_part for next iteration
    }
    if (half == 0) {
        atomicAdd(&bnsum[col], lsum);
        atomicAdd(&bnsq[col], lsq);
    }
}

// ---------------- BN finalize: a1 = g*rsqrt(var+eps), a0 = b - mean*a1 ----------------
__global__ void bn_finalize_kernel(const float* __restrict__ sum, const float* __restrict__ sq,
                                   const float* __restrict__ g, const float* __restrict__ b,
                                   float* __restrict__ a1, float* __restrict__ a0) {
    int c = threadIdx.x;
    if (c < HH) {
        float mean = sum[c] * (1.0f / NN);
        float var = sq[c] * (1.0f / NN) - mean * mean;
        float s = g[c] * rsqrtf(var + BN_EPS);
        a1[c] = s;
        a0[c] = b[c] - mean * s;
    }
}

// ---------------- BN apply + relu; write hbn and agg2 (init for conv2) ----------------
__global__ __launch_bounds__(256) void bn_apply_kernel(const float* __restrict__ h,
                                                       const float* __restrict__ a1,
                                                       const float* __restrict__ a0,
                                                       float* __restrict__ hbn,
                                                       float* __restrict__ agg2, int n4) {
    int i = blockIdx.x * 256 + threadIdx.x;
    if (i >= n4) return;
    int c4 = (i & 31) * 4;
    float4 hv = ((const float4*)h)[i];
    float4 s = *(const float4*)(a1 + c4);
    float4 o = *(const float4*)(a0 + c4);
    float4 r;
    r.x = fmaxf(fmaf(hv.x, s.x, o.x), 0.f);
    r.y = fmaxf(fmaf(hv.y, s.y, o.y), 0.f);
    r.z = fmaxf(fmaf(hv.z, s.z, o.z), 0.f);
    r.w = fmaxf(fmaf(hv.w, s.w, o.w), 0.f);
    ((float4*)hbn)[i] = r;
    ((float4*)agg2)[i] = r;
}

// ---------------- final: bn2+relu -> latent; classifier -> class_out ----------------
__global__ __launch_bounds__(256) void final_kernel(const float* __restrict__ h2,
                                                    const float* __restrict__ a1,
                                                    const float* __restrict__ a0,
                                                    const float* __restrict__ mw1,
                                                    const float* __restrict__ mb1,
                                                    const float* __restrict__ mw2,
                                                    const float* __restrict__ mb2,
                                                    float* __restrict__ latent,
                                                    float* __restrict__ cls) {
    __shared__ float s_lat[HH];
    __shared__ float s_m[HH];
    __shared__ float s_part[2][HH];
    __shared__ float s_w2[HH * CC];
    const int col = threadIdx.x & 127;
    const int half = threadIdx.x >> 7;

    float wr[64];
#pragma unroll
    for (int k = 0; k < 64; k++) wr[k] = mw1[(half * 64 + k) * HH + col];
    for (int i = threadIdx.x; i < HH * CC; i += 256) s_w2[i] = mw2[i];
    const float a1v = a1[col], a0v = a0[col], mb1v = mb1[col];
    __syncthreads();

    for (int row = blockIdx.x; row < NN; row += gridDim.x) {
        if (half == 0) {
            float v = fmaxf(fmaf(h2[(long long)row * HH + col], a1v, a0v), 0.f);
            latent[(long long)row * HH + col] = v;
            s_lat[col] = v;
        }
        __syncthreads();
        float p = 0.f;
#pragma unroll
        for (int k = 0; k < 64; k++) p = fmaf(s_lat[half * 64 + k], wr[k], p);
        s_part[half][col] = p;
        __syncthreads();
        if (half == 0) s_m[col] = fmaxf(s_part[0][col] + s_part[1][col] + mb1v, 0.f);
        __syncthreads();
        if (threadIdx.x < 2 * CC) {
            int c = threadIdx.x % CC;
            int kh = threadIdx.x / CC;
            float p2 = 0.f;
#pragma unroll
            for (int k = 0; k < 64; k++) p2 = fmaf(s_m[kh * 64 + k], s_w2[(kh * 64 + k) * CC + c], p2);
            s_part[kh][c] = p2;
        }
        __syncthreads();
        if (threadIdx.x < CC)
            cls[(long long)row * CC + threadIdx.x] =
                s_part[0][threadIdx.x] + s_part[1][threadIdx.x] + mb2[threadIdx.x];
        __syncthreads();
    }
}

extern "C" void kernel_launch(void* const* d_in, const int* in_sizes, int n_in,
                              void* d_out, int out_size, void* d_ws, size_t ws_size,
                              hipStream_t stream) {
    const float* x   = (const float*)d_in[0];
    const void* ei   = d_in[1];
    const float* w1a = (const float*)d_in[2];
    const float* b1a = (const float*)d_in[3];
    const float* w1b = (const float*)d_in[4];
    const float* b1b = (const float*)d_in[5];
    const float* w2a = (const float*)d_in[6];
    const float* b2a = (const float*)d_in[7];
    const float* w2b = (const float*)d_in[8];
    const float* b2b = (const float*)d_in[9];
    const float* bn1g = (const float*)d_in[10];
    const float* bn1b = (const float*)d_in[11];
    const float* bn2g = (const float*)d_in[12];
    const float* bn2b = (const float*)d_in[13];
    const float* mw1 = (const float*)d_in[14];
    const float* mb1 = (const float*)d_in[15];
    const float* mw2 = (const float*)d_in[16];
    const float* mb2 = (const float*)d_in[17];
    float* out = (float*)d_out;

    float* ws = (float*)d_ws;
    float* agg1 = ws;                       // 6,400,000 f32
    float* h    = agg1 + 6400000;           // 12,800,000 f32 (also h2)
    float* hbn  = h + 12800000;             // 12,800,000 f32
    float* agg2 = hbn + 12800000;           // 12,800,000 f32
    float* stats = agg2 + 12800000;         // sum1,sq1,sum2,sq2 (512) + a1/a0 x2 (512)
    int* flag = (int*)(stats + 1024);

    // zero BN accumulators
    hipMemsetAsync(stats, 0, 512 * sizeof(float), stream);
    detect_kernel<<<1, 64, 0, stream>>>((const unsigned int*)ei, flag);

    // conv1
    copy_kernel<<<(NN * FF / 4 + 255) / 256, 256, 0, stream>>>(x, agg1, NN * FF / 4);
    scatter_kernel<FF><<<(int)(((long long)EE * (FF / 4) + 255) / 256), 256, 0, stream>>>(ei, x, agg1, flag);
    mlp_kernel<FF><<<512, 256, 0, stream>>>(agg1, w1a, b1a, w1b, b1b, h, stats, stats + 128);
    bn_finalize_kernel<<<1, 128, 0, stream>>>(stats, stats + 128, bn1g, bn1b, stats + 512, stats + 640);
    bn_apply_kernel<<<(NN * HH / 4 + 255) / 256, 256, 0, stream>>>(h, stats + 512, stats + 640, hbn, agg2, NN * HH / 4);

    // conv2
    scatter_kernel<HH><<<(int)(((long long)EE * (HH / 4) + 255) / 256), 256, 0, stream>>>(ei, hbn, agg2, flag);
    mlp_kernel<HH><<<512, 256, 0, stream>>>(agg2, w2a, b2a, w2b, b2b, h, stats + 256, stats + 384);
    bn_finalize_kernel<<<1, 128, 0, stream>>>(stats + 256, stats + 384, bn2g, bn2b, stats + 768, stats + 896);

    // bn2 + relu + classifier
    final_kernel<<<512, 256, 0, stream>>>(h, stats + 768, stats + 896, mw1, mb1, mw2, mb2,
                                          out, out + (long long)NN * HH);
}

// Round 2
// 1263.575 us; speedup vs baseline: 3.8594x; 3.8594x over previous
//
#include <hip/hip_runtime.h>
#include <cstdint>

// GIN model: N=100000 nodes, F=64 in, H=128 hidden, C=10 classes, E=1600000 edges.
// R2: replace atomic push-scatter (3.28 GB of HBM writeback, 2679 us) with
// counting-sort -> CSR -> pull-gather (coalesced, atomic-free feature path).

#define NN 100000
#define FF 64
#define HH 128
#define CC 10
#define EE 1600000
#define BN_EPS 1e-5f
#define SCAN_B 512
#define NB_SCAN ((NN + SCAN_B - 1) / SCAN_B)  // 196

// ---------------- edge dtype detection (int64 vs int32) ----------------
__global__ void detect_kernel(const unsigned int* __restrict__ ei, int* __restrict__ flag) {
    if (threadIdx.x == 0) {
        bool i64 = (ei[1] == 0u) && (ei[3] == 0u) && (ei[5] == 0u) && (ei[7] == 0u);
        *flag = i64 ? 1 : 0;
    }
}

// ---------------- degree histogram ----------------
__global__ __launch_bounds__(256) void hist_kernel(const void* __restrict__ eiv,
                                                   const int* __restrict__ flag,
                                                   int* __restrict__ deg) {
    int e = blockIdx.x * 256 + threadIdx.x;
    if (e >= EE) return;
    int d;
    if (*flag) d = (int)((const long long*)eiv)[EE + e];
    else       d = ((const int*)eiv)[EE + e];
    atomicAdd(&deg[d], 1);
}

// ---------------- scan step A: per-block exclusive scan + block totals ----------------
__global__ __launch_bounds__(SCAN_B) void scanA_kernel(const int* __restrict__ deg,
                                                       int* __restrict__ partial,
                                                       int* __restrict__ blocksum) {
    __shared__ int s[SCAN_B];
    int i = blockIdx.x * SCAN_B + threadIdx.x;
    int v = (i < NN) ? deg[i] : 0;
    s[threadIdx.x] = v;
    __syncthreads();
    for (int off = 1; off < SCAN_B; off <<= 1) {
        int t = (threadIdx.x >= off) ? s[threadIdx.x - off] : 0;
        __syncthreads();
        s[threadIdx.x] += t;
        __syncthreads();
    }
    if (i < NN) partial[i] = s[threadIdx.x] - v;  // exclusive
    if (threadIdx.x == SCAN_B - 1) blocksum[blockIdx.x] = s[SCAN_B - 1];
}

// ---------------- scan step B: serial scan of block totals ----------------
__global__ void scanB_kernel(const int* __restrict__ blocksum, int* __restrict__ blockoff,
                             int* __restrict__ rowstart) {
    if (threadIdx.x == 0) {
        int run = 0;
        for (int b = 0; b < NB_SCAN; b++) { blockoff[b] = run; run += blocksum[b]; }
        rowstart[NN] = EE;
    }
}

// ---------------- scan step C: rowstart = partial + blockoff; cursor copy ----------------
__global__ __launch_bounds__(SCAN_B) void scanC_kernel(const int* __restrict__ partial,
                                                       const int* __restrict__ blockoff,
                                                       int* __restrict__ rowstart,
                                                       int* __restrict__ cursor) {
    int i = blockIdx.x * SCAN_B + threadIdx.x;
    if (i < NN) {
        int r = partial[i] + blockoff[blockIdx.x];
        rowstart[i] = r;
        cursor[i] = r;
    }
}

// ---------------- fill CSR adjacency ----------------
__global__ __launch_bounds__(256) void fill_kernel(const void* __restrict__ eiv,
                                                   const int* __restrict__ flag,
                                                   int* __restrict__ cursor,
                                                   int* __restrict__ eidx) {
    int e = blockIdx.x * 256 + threadIdx.x;
    if (e >= EE) return;
    int s, d;
    if (*flag) {
        const long long* p = (const long long*)eiv;
        s = (int)p[e];
        d = (int)p[EE + e];
    } else {
        const int* p = (const int*)eiv;
        s = p[e];
        d = p[EE + e];
    }
    int pos = atomicAdd(&cursor[d], 1);
    eidx[pos] = s;
}

// ---------------- pull gather: agg[i] = x[i] + sum_{j in N(i)} x[j] ----------------
template <int FDIM, int NPB>
__global__ __launch_bounds__(256) void gather_kernel(const float* __restrict__ xin,
                                                     const int* __restrict__ rowstart,
                                                     const int* __restrict__ eidx,
                                                     float* __restrict__ agg) {
    int node = blockIdx.x * NPB + threadIdx.x / FDIM;
    int lane = threadIdx.x & (FDIM - 1);
    if (node >= NN) return;
    int beg = rowstart[node], end = rowstart[node + 1];
    float acc = xin[(size_t)node * FDIM + lane];
    int j = beg;
    // 2-deep unroll for a little MLP (memory-level parallelism)
    for (; j + 1 < end; j += 2) {
        int s0 = eidx[j], s1 = eidx[j + 1];
        float v0 = xin[(size_t)s0 * FDIM + lane];
        float v1 = xin[(size_t)s1 * FDIM + lane];
        acc += v0 + v1;
    }
    if (j < end) acc += xin[(size_t)eidx[j] * FDIM + lane];
    agg[(size_t)node * FDIM + lane] = acc;
}

// ---------------- MLP: out = relu(in@wa+ba)@wb+bb, plus BN stats ----------------
template <int KIN>
__global__ __launch_bounds__(256) void mlp_kernel(const float* __restrict__ in,
                                                  const float* __restrict__ wa,
                                                  const float* __restrict__ ba,
                                                  const float* __restrict__ wb,
                                                  const float* __restrict__ bb,
                                                  float* __restrict__ out,
                                                  float* __restrict__ bnsum,
                                                  float* __restrict__ bnsq) {
    constexpr int KH = KIN / 2;
    __shared__ float s_in[KIN];
    __shared__ float s_h1[HH];
    __shared__ float s_part[2][HH];
    const int col = threadIdx.x & 127;
    const int half = threadIdx.x >> 7;

    float wra[KH];
#pragma unroll
    for (int k = 0; k < KH; k++) wra[k] = wa[(half * KH + k) * HH + col];
    float wrb[64];
#pragma unroll
    for (int k = 0; k < 64; k++) wrb[k] = wb[(half * 64 + k) * HH + col];
    const float bav = ba[col], bbv = bb[col];

    float lsum = 0.f, lsq = 0.f;
    for (int row = blockIdx.x; row < NN; row += gridDim.x) {
        if (threadIdx.x < KIN) s_in[threadIdx.x] = in[(long long)row * KIN + threadIdx.x];
        __syncthreads();
        float p = 0.f;
#pragma unroll
        for (int k = 0; k < KH; k++) p = fmaf(s_in[half * KH + k], wra[k], p);
        s_part[half][col] = p;
        __syncthreads();
        if (half == 0) {
            s_h1[col] = fmaxf(s_part[0][col] + s_part[1][col] + bav, 0.f);
        }
        __syncthreads();
        float p2 = 0.f;
#pragma unroll
        for (int k = 0; k < 64; k++) p2 = fmaf(s_h1[half * 64 + k], wrb[k], p2);
        s_part[half][col] = p2;
        __syncthreads();
        if (half == 0) {
            float v = s_part[0][col] + s_part[1][col] + bbv;
            out[(long long)row * HH + col] = v;
            lsum += v;
            lsq += v * v;
        }
        __syncthreads();
    }
    if (half == 0) {
        atomicAdd(&bnsum[col], lsum);
        atomicAdd(&bnsq[col], lsq);
    }
}

// ---------------- BN finalize ----------------
__global__ void bn_finalize_kernel(const float* __restrict__ sum, const float* __restrict__ sq,
                                   const float* __restrict__ g, const float* __restrict__ b,
                                   float* __restrict__ a1, float* __restrict__ a0) {
    int c = threadIdx.x;
    if (c < HH) {
        float mean = sum[c] * (1.0f / NN);
        float var = sq[c] * (1.0f / NN) - mean * mean;
        float s = g[c] * rsqrtf(var + BN_EPS);
        a1[c] = s;
        a0[c] = b[c] - mean * s;
    }
}

// ---------------- BN apply + relu -> hbn ----------------
__global__ __launch_bounds__(256) void bn_apply_kernel(const float* __restrict__ h,
                                                       const float* __restrict__ a1,
                                                       const float* __restrict__ a0,
                                                       float* __restrict__ hbn, int n4) {
    int i = blockIdx.x * 256 + threadIdx.x;
    if (i >= n4) return;
    int c4 = (i & 31) * 4;
    float4 hv = ((const float4*)h)[i];
    float4 s = *(const float4*)(a1 + c4);
    float4 o = *(const float4*)(a0 + c4);
    float4 r;
    r.x = fmaxf(fmaf(hv.x, s.x, o.x), 0.f);
    r.y = fmaxf(fmaf(hv.y, s.y, o.y), 0.f);
    r.z = fmaxf(fmaf(hv.z, s.z, o.z), 0.f);
    r.w = fmaxf(fmaf(hv.w, s.w, o.w), 0.f);
    ((float4*)hbn)[i] = r;
}

// ---------------- final: bn2+relu -> latent; classifier -> class_out ----------------
__global__ __launch_bounds__(256) void final_kernel(const float* __restrict__ h2,
                                                    const float* __restrict__ a1,
                                                    const float* __restrict__ a0,
                                                    const float* __restrict__ mw1,
                                                    const float* __restrict__ mb1,
                                                    const float* __restrict__ mw2,
                                                    const float* __restrict__ mb2,
                                                    float* __restrict__ latent,
                                                    float* __restrict__ cls) {
    __shared__ float s_lat[HH];
    __shared__ float s_m[HH];
    __shared__ float s_part[2][HH];
    __shared__ float s_w2[HH * CC];
    const int col = threadIdx.x & 127;
    const int half = threadIdx.x >> 7;

    float wr[64];
#pragma unroll
    for (int k = 0; k < 64; k++) wr[k] = mw1[(half * 64 + k) * HH + col];
    for (int i = threadIdx.x; i < HH * CC; i += 256) s_w2[i] = mw2[i];
    const float a1v = a1[col], a0v = a0[col], mb1v = mb1[col];
    __syncthreads();

    for (int row = blockIdx.x; row < NN; row += gridDim.x) {
        if (half == 0) {
            float v = fmaxf(fmaf(h2[(long long)row * HH + col], a1v, a0v), 0.f);
            latent[(long long)row * HH + col] = v;
            s_lat[col] = v;
        }
        __syncthreads();
        float p = 0.f;
#pragma unroll
        for (int k = 0; k < 64; k++) p = fmaf(s_lat[half * 64 + k], wr[k], p);
        s_part[half][col] = p;
        __syncthreads();
        if (half == 0) s_m[col] = fmaxf(s_part[0][col] + s_part[1][col] + mb1v, 0.f);
        __syncthreads();
        if (threadIdx.x < 2 * CC) {
            int c = threadIdx.x % CC;
            int kh = threadIdx.x / CC;
            float p2 = 0.f;
#pragma unroll
            for (int k = 0; k < 64; k++) p2 = fmaf(s_m[kh * 64 + k], s_w2[(kh * 64 + k) * CC + c], p2);
            s_part[kh][c] = p2;
        }
        __syncthreads();
        if (threadIdx.x < CC)
            cls[(long long)row * CC + threadIdx.x] =
                s_part[0][threadIdx.x] + s_part[1][threadIdx.x] + mb2[threadIdx.x];
        __syncthreads();
    }
}

extern "C" void kernel_launch(void* const* d_in, const int* in_sizes, int n_in,
                              void* d_out, int out_size, void* d_ws, size_t ws_size,
                              hipStream_t stream) {
    const float* x   = (const float*)d_in[0];
    const void* ei   = d_in[1];
    const float* w1a = (const float*)d_in[2];
    const float* b1a = (const float*)d_in[3];
    const float* w1b = (const float*)d_in[4];
    const float* b1b = (const float*)d_in[5];
    const float* w2a = (const float*)d_in[6];
    const float* b2a = (const float*)d_in[7];
    const float* w2b = (const float*)d_in[8];
    const float* b2b = (const float*)d_in[9];
    const float* bn1g = (const float*)d_in[10];
    const float* bn1b = (const float*)d_in[11];
    const float* bn2g = (const float*)d_in[12];
    const float* bn2b = (const float*)d_in[13];
    const float* mw1 = (const float*)d_in[14];
    const float* mb1 = (const float*)d_in[15];
    const float* mw2 = (const float*)d_in[16];
    const float* mb2 = (const float*)d_in[17];
    float* out = (float*)d_out;

    float* ws = (float*)d_ws;
    float* agg1 = ws;                       // 6,400,000 f32 (25.6 MB)
    float* h    = agg1 + 6400000;           // 12,800,000 f32 (h1 then h2)
    float* hbn  = h + 12800000;             // 12,800,000 f32
    float* agg2 = hbn + 12800000;           // 12,800,000 f32
    float* stats = agg2 + 12800000;         // 1024 f32: sum1,sq1,sum2,sq2,a1/a0 x2
    int* eidx = (int*)(stats + 1024);       // E ints (6.4 MB)
    int* rowstart = eidx + EE;              // N+1 ints
    int* flag = rowstart + NN + 1;          // 1 int
    // transient int arrays (dead before gather1 writes agg1) alias agg1:
    int* deg = (int*)agg1;                  // N ints
    int* partial = deg + NN;                // N ints
    int* cursor = partial + NN;             // N ints
    int* blocksum = cursor + NN;            // NB_SCAN ints
    int* blockoff = blocksum + 256;         // NB_SCAN ints

    hipMemsetAsync(stats, 0, 512 * sizeof(float), stream);
    hipMemsetAsync(deg, 0, NN * sizeof(int), stream);
    detect_kernel<<<1, 64, 0, stream>>>((const unsigned int*)ei, flag);

    // ---- build CSR (counting sort by dst) ----
    hist_kernel<<<(EE + 255) / 256, 256, 0, stream>>>(ei, flag, deg);
    scanA_kernel<<<NB_SCAN, SCAN_B, 0, stream>>>(deg, partial, blocksum);
    scanB_kernel<<<1, 64, 0, stream>>>(blocksum, blockoff, rowstart);
    scanC_kernel<<<NB_SCAN, SCAN_B, 0, stream>>>(partial, blockoff, rowstart, cursor);
    fill_kernel<<<(EE + 255) / 256, 256, 0, stream>>>(ei, flag, cursor, eidx);

    // ---- conv1 ----
    gather_kernel<FF, 4><<<(NN + 3) / 4, 256, 0, stream>>>(x, rowstart, eidx, agg1);
    mlp_kernel<FF><<<512, 256, 0, stream>>>(agg1, w1a, b1a, w1b, b1b, h, stats, stats + 128);
    bn_finalize_kernel<<<1, 128, 0, stream>>>(stats, stats + 128, bn1g, bn1b, stats + 512, stats + 640);
    bn_apply_kernel<<<(NN * HH / 4 + 255) / 256, 256, 0, stream>>>(h, stats + 512, stats + 640, hbn, NN * HH / 4);

    // ---- conv2 ----
    gather_kernel<HH, 2><<<(NN + 1) / 2, 256, 0, stream>>>(hbn, rowstart, eidx, agg2);
    mlp_kernel<HH><<<512, 256, 0, stream>>>(agg2, w2a, b2a, w2b, b2b, h, stats + 256, stats + 384);
    bn_finalize_kernel<<<1, 128, 0, stream>>>(stats + 256, stats + 384, bn2g, bn2b, stats + 768, stats + 896);

    // ---- bn2 + relu + classifier ----
    final_kernel<<<512, 256, 0, stream>>>(h, stats + 768, stats + 896, mw1, mb1, mw2, mb2,
                                          out, out + (long long)NN * HH);
}

// Round 3
// 652.583 us; speedup vs baseline: 7.4728x; 1.9363x over previous
//
#include <hip/hip_runtime.h>
#include <cstdint>

// GIN model: N=100000, F=64, H=128, C=10, E=1600000.
// R3: MFMA bf16 GEMMs for all MLPs/classifier; bf16 intermediates; CSR pull-gather.

#define NN 100000
#define FF 64
#define HH 128
#define CC 10
#define EE 1600000
#define BN_EPS 1e-5f
#define SCAN_B 512
#define NB_SCAN ((NN + SCAN_B - 1) / SCAN_B)
#define MBLK 128
#define NBLK_LIN ((NN + MBLK - 1) / MBLK)  // 782

typedef __attribute__((ext_vector_type(8))) short bf16x8;
typedef __attribute__((ext_vector_type(4))) float f32x4;
typedef unsigned short ushort_t;

__device__ inline unsigned short f2bf(float f) {
    unsigned int u = __float_as_uint(f);
    unsigned int r = (u + 0x7fffu + ((u >> 16) & 1u)) >> 16;
    return (unsigned short)r;
}
__device__ inline float b2f(unsigned short h) {
    return __uint_as_float(((unsigned int)h) << 16);
}
__device__ inline unsigned int pack2(float a, float b) {
    return (unsigned int)f2bf(a) | ((unsigned int)f2bf(b) << 16);
}

// ---------------- edge dtype detection ----------------
__global__ void detect_kernel(const unsigned int* __restrict__ ei, int* __restrict__ flag) {
    if (threadIdx.x == 0) {
        bool i64 = (ei[1] == 0u) && (ei[3] == 0u) && (ei[5] == 0u) && (ei[7] == 0u);
        *flag = i64 ? 1 : 0;
    }
}

// ---------------- CSR build ----------------
__global__ __launch_bounds__(256) void hist_kernel(const void* __restrict__ eiv,
                                                   const int* __restrict__ flag,
                                                   int* __restrict__ deg) {
    int e = blockIdx.x * 256 + threadIdx.x;
    if (e >= EE) return;
    int d;
    if (*flag) d = (int)((const long long*)eiv)[EE + e];
    else       d = ((const int*)eiv)[EE + e];
    atomicAdd(&deg[d], 1);
}

__global__ __launch_bounds__(SCAN_B) void scanA_kernel(const int* __restrict__ deg,
                                                       int* __restrict__ partial,
                                                       int* __restrict__ blocksum) {
    __shared__ int s[SCAN_B];
    int i = blockIdx.x * SCAN_B + threadIdx.x;
    int v = (i < NN) ? deg[i] : 0;
    s[threadIdx.x] = v;
    __syncthreads();
    for (int off = 1; off < SCAN_B; off <<= 1) {
        int t = (threadIdx.x >= off) ? s[threadIdx.x - off] : 0;
        __syncthreads();
        s[threadIdx.x] += t;
        __syncthreads();
    }
    if (i < NN) partial[i] = s[threadIdx.x] - v;
    if (threadIdx.x == SCAN_B - 1) blocksum[blockIdx.x] = s[SCAN_B - 1];
}

__global__ void scanB_kernel(const int* __restrict__ blocksum, int* __restrict__ blockoff,
                             int* __restrict__ rowstart) {
    if (threadIdx.x == 0) {
        int run = 0;
        for (int b = 0; b < NB_SCAN; b++) { blockoff[b] = run; run += blocksum[b]; }
        rowstart[NN] = EE;
    }
}

__global__ __launch_bounds__(SCAN_B) void scanC_kernel(const int* __restrict__ partial,
                                                       const int* __restrict__ blockoff,
                                                       int* __restrict__ rowstart,
                                                       int* __restrict__ cursor) {
    int i = blockIdx.x * SCAN_B + threadIdx.x;
    if (i < NN) {
        int r = partial[i] + blockoff[blockIdx.x];
        rowstart[i] = r;
        cursor[i] = r;
    }
}

__global__ __launch_bounds__(256) void fill_kernel(const void* __restrict__ eiv,
                                                   const int* __restrict__ flag,
                                                   int* __restrict__ cursor,
                                                   int* __restrict__ eidx) {
    int e = blockIdx.x * 256 + threadIdx.x;
    if (e >= EE) return;
    int s, d;
    if (*flag) {
        const long long* p = (const long long*)eiv;
        s = (int)p[e];
        d = (int)p[EE + e];
    } else {
        const int* p = (const int*)eiv;
        s = p[e];
        d = p[EE + e];
    }
    int pos = atomicAdd(&cursor[d], 1);
    eidx[pos] = s;
}

// ---------------- x f32 -> bf16 ----------------
__global__ __launch_bounds__(256) void cvt_kernel(const float* __restrict__ x,
                                                  unsigned short* __restrict__ xb, int n8) {
    int i = blockIdx.x * 256 + threadIdx.x;
    if (i >= n8) return;
    float4 a = ((const float4*)x)[i * 2];
    float4 b = ((const float4*)x)[i * 2 + 1];
    uint4 o;
    o.x = pack2(a.x, a.y); o.y = pack2(a.z, a.w);
    o.z = pack2(b.x, b.y); o.w = pack2(b.z, b.w);
    ((uint4*)xb)[i] = o;
}

// ---------------- pull gather (bf16): agg[i] = x[i] + sum_{j} x[j] ----------------
template <int FDIM, int NPB>
__global__ __launch_bounds__(256) void gather_bf_kernel(const unsigned short* __restrict__ xin,
                                                        const int* __restrict__ rowstart,
                                                        const int* __restrict__ eidx,
                                                        unsigned short* __restrict__ agg) {
    constexpr int LPN = FDIM / 2;  // lanes per node (2 bf16 per lane)
    int node = blockIdx.x * NPB + threadIdx.x / LPN;
    int lane = threadIdx.x % LPN;
    if (node >= NN) return;
    int beg = rowstart[node], end = rowstart[node + 1];
    unsigned int self = *(const unsigned int*)(xin + (size_t)node * FDIM + lane * 2);
    float ax = b2f((unsigned short)(self & 0xffff));
    float ay = b2f((unsigned short)(self >> 16));
    int j = beg;
    for (; j + 1 < end; j += 2) {
        int s0 = eidx[j], s1 = eidx[j + 1];
        unsigned int v0 = *(const unsigned int*)(xin + (size_t)s0 * FDIM + lane * 2);
        unsigned int v1 = *(const unsigned int*)(xin + (size_t)s1 * FDIM + lane * 2);
        ax += b2f((unsigned short)(v0 & 0xffff)) + b2f((unsigned short)(v1 & 0xffff));
        ay += b2f((unsigned short)(v0 >> 16)) + b2f((unsigned short)(v1 >> 16));
    }
    if (j < end) {
        unsigned int v0 = *(const unsigned int*)(xin + (size_t)eidx[j] * FDIM + lane * 2);
        ax += b2f((unsigned short)(v0 & 0xffff));
        ay += b2f((unsigned short)(v0 >> 16));
    }
    *(unsigned int*)(agg + (size_t)node * FDIM + lane * 2) = pack2(ax, ay);
}

// ---------------- MFMA linear layer: out = act(in[N][KIN] @ W[KIN][128] + b) ----------------
// MODE 0: relu, no stats. MODE 1: no relu, accumulate BN stats.
template <int KIN, int MODE>
__global__ __launch_bounds__(256) void lin_kernel(const unsigned short* __restrict__ in,
                                                  const float* __restrict__ W,
                                                  const float* __restrict__ bias,
                                                  unsigned short* __restrict__ out,
                                                  float* __restrict__ bnsum,
                                                  float* __restrict__ bnsq) {
    constexpr int KLD = KIN + 8;           // padded LDS stride (16B aligned, 2-way banks)
    constexpr int CH = KIN / 8;            // uint4 chunks per input row
    __shared__ __attribute__((aligned(16))) unsigned short smem[MBLK * KLD + 128 * KLD];
    __shared__ float sSt[256];
    unsigned short* sA = smem;             // A tile MBLK x KLD
    unsigned short* sW = smem + MBLK * KLD;  // W^T: 128 x KLD (sW[n*KLD+k] = W[k][n])
    unsigned short* sO = smem;             // output stage overlay: MBLK x 136

    const int tid = threadIdx.x;
    const int wave = tid >> 6, lane = tid & 63;
    const int quad = lane >> 4, l16 = lane & 15;
    const long long row0 = (long long)blockIdx.x * MBLK;

    if (MODE == 1) sSt[tid] = 0.f;

    // stage W^T (bf16)
    for (int i = tid; i < KIN * 128; i += 256) {
        int k = i >> 7, n = i & 127;
        sW[n * KLD + k] = f2bf(W[i]);
    }
    // stage A tile
    for (int i = tid; i < MBLK * CH; i += 256) {
        int r = i / CH, c = i % CH;
        uint4 v = {0u, 0u, 0u, 0u};
        if (row0 + r < NN) v = *(const uint4*)(in + (row0 + r) * KIN + c * 8);
        *(uint4*)(sA + r * KLD + c * 8) = v;
    }
    __syncthreads();

    f32x4 acc[2][8];
#pragma unroll
    for (int t = 0; t < 2; t++)
#pragma unroll
        for (int n = 0; n < 8; n++) acc[t][n] = 0.f;

#pragma unroll
    for (int ks = 0; ks < KIN / 32; ks++) {
        bf16x8 a0 = *(const bf16x8*)(sA + (wave * 32 + l16) * KLD + ks * 32 + quad * 8);
        bf16x8 a1 = *(const bf16x8*)(sA + (wave * 32 + 16 + l16) * KLD + ks * 32 + quad * 8);
#pragma unroll
        for (int nt = 0; nt < 8; nt++) {
            bf16x8 b = *(const bf16x8*)(sW + (nt * 16 + l16) * KLD + ks * 32 + quad * 8);
            acc[0][nt] = __builtin_amdgcn_mfma_f32_16x16x32_bf16(a0, b, acc[0][nt], 0, 0, 0);
            acc[1][nt] = __builtin_amdgcn_mfma_f32_16x16x32_bf16(a1, b, acc[1][nt], 0, 0, 0);
        }
    }
    __syncthreads();  // A/W reads done; reuse smem as output stage

    // epilogue: value (row, col) = (wave*32 + t*16 + quad*4 + r, nt*16 + l16)
#pragma unroll
    for (int nt = 0; nt < 8; nt++) {
        const int col = nt * 16 + l16;
        const float bcol = bias[col];
        float ls = 0.f, lq = 0.f;
#pragma unroll
        for (int t = 0; t < 2; t++) {
#pragma unroll
            for (int r = 0; r < 4; r++) {
                int rl = wave * 32 + t * 16 + quad * 4 + r;
                float v = acc[t][nt][r] + bcol;
                if (MODE == 0) v = fmaxf(v, 0.f);
                if (MODE == 1 && row0 + rl < NN) { ls += v; lq += v * v; }
                sO[rl * 136 + col] = f2bf(v);
            }
        }
        if (MODE == 1) {
            ls += __shfl_down(ls, 32); ls += __shfl_down(ls, 16);
            lq += __shfl_down(lq, 32); lq += __shfl_down(lq, 16);
            if (lane < 16) { atomicAdd(&sSt[col], ls); atomicAdd(&sSt[128 + col], lq); }
        }
    }
    __syncthreads();

    for (int i = tid; i < MBLK * 16; i += 256) {
        int r = i >> 4, c = i & 15;
        if (row0 + r < NN)
            *(uint4*)(out + (row0 + r) * 128 + c * 8) = *(const uint4*)(sO + r * 136 + c * 8);
    }
    if (MODE == 1) {
        if (tid < 128) atomicAdd(&bnsum[tid], sSt[tid]);
        else if (tid < 256) atomicAdd(&bnsq[tid - 128], sSt[tid]);
    }
}

// ---------------- classifier head: cls = in[N][128] @ mw2[128][10] + mb2 (f32 out) ----------------
__global__ __launch_bounds__(256) void lin_cls_kernel(const unsigned short* __restrict__ in,
                                                      const float* __restrict__ W2,
                                                      const float* __restrict__ b2,
                                                      float* __restrict__ cls) {
    constexpr int KLD = 136;
    __shared__ __attribute__((aligned(16))) unsigned short smem[MBLK * KLD + 16 * KLD];
    unsigned short* sA = smem;
    unsigned short* sW = smem + MBLK * KLD;
    float* sOf = (float*)smem;  // overlay after sync: MBLK x 10 f32

    const int tid = threadIdx.x;
    const int wave = tid >> 6, lane = tid & 63;
    const int quad = lane >> 4, l16 = lane & 15;
    const long long row0 = (long long)blockIdx.x * MBLK;

    for (int i = tid; i < 16 * 128; i += 256) {
        int n = i & 15, k = i >> 4;
        sW[n * KLD + k] = (n < CC) ? f2bf(W2[k * CC + n]) : (unsigned short)0;
    }
    for (int i = tid; i < MBLK * 16; i += 256) {
        int r = i >> 4, c = i & 15;
        uint4 v = {0u, 0u, 0u, 0u};
        if (row0 + r < NN) v = *(const uint4*)(in + (row0 + r) * 128 + c * 8);
        *(uint4*)(sA + r * KLD + c * 8) = v;
    }
    __syncthreads();

    f32x4 acc[2];
    acc[0] = 0.f; acc[1] = 0.f;
#pragma unroll
    for (int ks = 0; ks < 4; ks++) {
        bf16x8 a0 = *(const bf16x8*)(sA + (wave * 32 + l16) * KLD + ks * 32 + quad * 8);
        bf16x8 a1 = *(const bf16x8*)(sA + (wave * 32 + 16 + l16) * KLD + ks * 32 + quad * 8);
        bf16x8 b = *(const bf16x8*)(sW + l16 * KLD + ks * 32 + quad * 8);
        acc[0] = __builtin_amdgcn_mfma_f32_16x16x32_bf16(a0, b, acc[0], 0, 0, 0);
        acc[1] = __builtin_amdgcn_mfma_f32_16x16x32_bf16(a1, b, acc[1], 0, 0, 0);
    }
    __syncthreads();

    if (l16 < CC) {
        const float bc = b2[l16];
#pragma unroll
        for (int t = 0; t < 2; t++)
#pragma unroll
            for (int r = 0; r < 4; r++) {
                int rl = wave * 32 + t * 16 + quad * 4 + r;
                sOf[rl * CC + l16] = acc[t][r] + bc;
            }
    }
    __syncthreads();
    for (int i = tid; i < MBLK * CC; i += 256) {
        long long gi = row0 * CC + i;
        if (gi < (long long)NN * CC) cls[gi] = sOf[i];
    }
}

// ---------------- BN finalize ----------------
__global__ void bn_finalize_kernel(const float* __restrict__ sum, const float* __restrict__ sq,
                                   const float* __restrict__ g, const float* __restrict__ b,
                                   float* __restrict__ a1, float* __restrict__ a0) {
    int c = threadIdx.x;
    if (c < HH) {
        float mean = sum[c] * (1.0f / NN);
        float var = sq[c] * (1.0f / NN) - mean * mean;
        float s = g[c] * rsqrtf(var + BN_EPS);
        a1[c] = s;
        a0[c] = b[c] - mean * s;
    }
}

// ---------------- BN apply + relu (bf16 -> bf16) ----------------
__global__ __launch_bounds__(256) void bn_apply_kernel(const unsigned short* __restrict__ h,
                                                       const float* __restrict__ a1,
                                                       const float* __restrict__ a0,
                                                       unsigned short* __restrict__ hbn, int n8) {
    int i = blockIdx.x * 256 + threadIdx.x;
    if (i >= n8) return;
    int c0 = (i & 15) * 8;
    uint4 hv = ((const uint4*)h)[i];
    const unsigned int* w = (const unsigned int*)&hv;
    uint4 o;
    unsigned int* ow = (unsigned int*)&o;
#pragma unroll
    for (int p = 0; p < 4; p++) {
        float v0 = b2f((unsigned short)(w[p] & 0xffff));
        float v1 = b2f((unsigned short)(w[p] >> 16));
        int c = c0 + p * 2;
        v0 = fmaxf(fmaf(v0, a1[c], a0[c]), 0.f);
        v1 = fmaxf(fmaf(v1, a1[c + 1], a0[c + 1]), 0.f);
        ow[p] = pack2(v0, v1);
    }
    ((uint4*)hbn)[i] = o;
}

// ---------------- latent: bn2+relu -> latent f32 (d_out) + latb bf16 ----------------
__global__ __launch_bounds__(256) void latent_kernel(const unsigned short* __restrict__ h2,
                                                     const float* __restrict__ a1,
                                                     const float* __restrict__ a0,
                                                     float* __restrict__ latent,
                                                     unsigned short* __restrict__ latb, int n8) {
    int i = blockIdx.x * 256 + threadIdx.x;
    if (i >= n8) return;
    int c0 = (i & 15) * 8;
    uint4 hv = ((const uint4*)h2)[i];
    const unsigned int* w = (const unsigned int*)&hv;
    float vs[8];
#pragma unroll
    for (int p = 0; p < 4; p++) {
        int c = c0 + p * 2;
        vs[p * 2]     = fmaxf(fmaf(b2f((unsigned short)(w[p] & 0xffff)), a1[c], a0[c]), 0.f);
        vs[p * 2 + 1] = fmaxf(fmaf(b2f((unsigned short)(w[p] >> 16)), a1[c + 1], a0[c + 1]), 0.f);
    }
    float4 f0 = {vs[0], vs[1], vs[2], vs[3]};
    float4 f1 = {vs[4], vs[5], vs[6], vs[7]};
    ((float4*)latent)[i * 2] = f0;
    ((float4*)latent)[i * 2 + 1] = f1;
    uint4 o;
    o.x = pack2(vs[0], vs[1]); o.y = pack2(vs[2], vs[3]);
    o.z = pack2(vs[4], vs[5]); o.w = pack2(vs[6], vs[7]);
    ((uint4*)latb)[i] = o;
}

extern "C" void kernel_launch(void* const* d_in, const int* in_sizes, int n_in,
                              void* d_out, int out_size, void* d_ws, size_t ws_size,
                              hipStream_t stream) {
    const float* x   = (const float*)d_in[0];
    const void* ei   = d_in[1];
    const float* w1a = (const float*)d_in[2];
    const float* b1a = (const float*)d_in[3];
    const float* w1b = (const float*)d_in[4];
    const float* b1b = (const float*)d_in[5];
    const float* w2a = (const float*)d_in[6];
    const float* b2a = (const float*)d_in[7];
    const float* w2b = (const float*)d_in[8];
    const float* b2b = (const float*)d_in[9];
    const float* bn1g = (const float*)d_in[10];
    const float* bn1b = (const float*)d_in[11];
    const float* bn2g = (const float*)d_in[12];
    const float* bn2b = (const float*)d_in[13];
    const float* mw1 = (const float*)d_in[14];
    const float* mb1 = (const float*)d_in[15];
    const float* mw2 = (const float*)d_in[16];
    const float* mb2 = (const float*)d_in[17];
    float* out = (float*)d_out;

    char* w = (char*)d_ws;
    unsigned short* agg1 = (unsigned short*)w;  w += (size_t)NN * FF * 2;   // 12.8 MB
    unsigned short* t1   = (unsigned short*)w;  w += (size_t)NN * HH * 2;   // 25.6 MB (t2, m)
    unsigned short* h    = (unsigned short*)w;  w += (size_t)NN * HH * 2;   // h1, then h2
    unsigned short* hbn  = (unsigned short*)w;  w += (size_t)NN * HH * 2;   // then latb
    unsigned short* agg2 = (unsigned short*)w;  w += (size_t)NN * HH * 2;
    unsigned short* xb   = (unsigned short*)w;  w += (size_t)NN * FF * 2;
    float* stats = (float*)w;                   w += 1024 * 4;
    int* eidx = (int*)w;                        w += (size_t)EE * 4;
    int* rowstart = (int*)w;                    w += (NN + 2) * 4;
    int* flag = (int*)w;                        w += 16;
    int* deg = (int*)w;                         w += NN * 4;
    int* partial = (int*)w;                     w += NN * 4;
    int* cursor = (int*)w;                      w += NN * 4;
    int* blocksum = (int*)w;                    w += 256 * 4;
    int* blockoff = (int*)w;                    w += 256 * 4;

    hipMemsetAsync(stats, 0, 512 * sizeof(float), stream);
    hipMemsetAsync(deg, 0, NN * sizeof(int), stream);
    detect_kernel<<<1, 64, 0, stream>>>((const unsigned int*)ei, flag);

    // CSR
    hist_kernel<<<(EE + 255) / 256, 256, 0, stream>>>(ei, flag, deg);
    scanA_kernel<<<NB_SCAN, SCAN_B, 0, stream>>>(deg, partial, blocksum);
    scanB_kernel<<<1, 64, 0, stream>>>(blocksum, blockoff, rowstart);
    scanC_kernel<<<NB_SCAN, SCAN_B, 0, stream>>>(partial, blockoff, rowstart, cursor);
    fill_kernel<<<(EE + 255) / 256, 256, 0, stream>>>(ei, flag, cursor, eidx);

    // conv1
    cvt_kernel<<<(NN * FF / 8 + 255) / 256, 256, 0, stream>>>(x, xb, NN * FF / 8);
    gather_bf_kernel<FF, 8><<<(NN + 7) / 8, 256, 0, stream>>>(xb, rowstart, eidx, agg1);
    lin_kernel<FF, 0><<<NBLK_LIN, 256, 0, stream>>>(agg1, w1a, b1a, t1, nullptr, nullptr);
    lin_kernel<HH, 1><<<NBLK_LIN, 256, 0, stream>>>(t1, w1b, b1b, h, stats, stats + 128);
    bn_finalize_kernel<<<1, 128, 0, stream>>>(stats, stats + 128, bn1g, bn1b, stats + 512, stats + 640);
    bn_apply_kernel<<<(NN * HH / 8 + 255) / 256, 256, 0, stream>>>(h, stats + 512, stats + 640, hbn, NN * HH / 8);

    // conv2
    gather_bf_kernel<HH, 4><<<(NN + 3) / 4, 256, 0, stream>>>(hbn, rowstart, eidx, agg2);
    lin_kernel<HH, 0><<<NBLK_LIN, 256, 0, stream>>>(agg2, w2a, b2a, t1, nullptr, nullptr);
    lin_kernel<HH, 1><<<NBLK_LIN, 256, 0, stream>>>(t1, w2b, b2b, h, stats + 256, stats + 384);
    bn_finalize_kernel<<<1, 128, 0, stream>>>(stats + 256, stats + 384, bn2g, bn2b, stats + 768, stats + 896);

    // latent + classifier
    latent_kernel<<<(NN * HH / 8 + 255) / 256, 256, 0, stream>>>(h, stats + 768, stats + 896,
                                                                 out, hbn, NN * HH / 8);
    lin_kernel<HH, 0><<<NBLK_LIN, 256, 0, stream>>>(hbn, mw1, mb1, t1, nullptr, nullptr);
    lin_cls_kernel<<<NBLK_LIN, 256, 0, stream>>>(t1, mw2, mb2, out + (size_t)NN * HH);
}

// Round 4
// 553.593 us; speedup vs baseline: 8.8090x; 1.1788x over previous
//
#include <hip/hip_runtime.h>
#include <cstdint>

// GIN model: N=100000, F=64, H=128, C=10, E=1600000.
// R4: CSR build via two-level LDS bucket sort (was: global-atomic hist + scattered
// fill with 16x write amplification, 105 MB writeback, 165 us combined).

#define NN 100000
#define FF 64
#define HH 128
#define CC 10
#define EE 1600000
#define BN_EPS 1e-5f
#define MBLK 128
#define NBLK_LIN ((NN + MBLK - 1) / MBLK)  // 782
#define BSHIFT 7
#define NBUCK ((NN + 127) / 128)           // 782
#define CHUNK 16384
#define NB_CH ((EE + CHUNK - 1) / CHUNK)   // 98

typedef __attribute__((ext_vector_type(8))) short bf16x8;
typedef __attribute__((ext_vector_type(4))) float f32x4;

__device__ inline unsigned short f2bf(float f) {
    unsigned int u = __float_as_uint(f);
    unsigned int r = (u + 0x7fffu + ((u >> 16) & 1u)) >> 16;
    return (unsigned short)r;
}
__device__ inline float b2f(unsigned short h) {
    return __uint_as_float(((unsigned int)h) << 16);
}
__device__ inline unsigned int pack2(float a, float b) {
    return (unsigned int)f2bf(a) | ((unsigned int)f2bf(b) << 16);
}

// ---------------- edge dtype detection ----------------
__global__ void detect_kernel(const unsigned int* __restrict__ ei, int* __restrict__ flag) {
    if (threadIdx.x == 0) {
        bool i64 = (ei[1] == 0u) && (ei[3] == 0u) && (ei[5] == 0u) && (ei[7] == 0u);
        *flag = i64 ? 1 : 0;
    }
}

__device__ inline int edge_dst(const void* eiv, int f, int e) {
    return f ? (int)((const long long*)eiv)[EE + e] : ((const int*)eiv)[EE + e];
}
__device__ inline int edge_src(const void* eiv, int f, int e) {
    return f ? (int)((const long long*)eiv)[e] : ((const int*)eiv)[e];
}

// ---------------- P1: coarse bucket histogram (LDS-staged) ----------------
__global__ __launch_bounds__(256) void p1_hist_kernel(const void* __restrict__ eiv,
                                                      const int* __restrict__ flag,
                                                      int* __restrict__ gbcount) {
    __shared__ int hist[NBUCK];
    const int tid = threadIdx.x;
    const int f = *flag;
    for (int i = tid; i < NBUCK; i += 256) hist[i] = 0;
    __syncthreads();
    int beg = blockIdx.x * CHUNK, end = min(beg + CHUNK, EE);
    for (int e = beg + tid; e < end; e += 256)
        atomicAdd(&hist[edge_dst(eiv, f, e) >> BSHIFT], 1);
    __syncthreads();
    for (int i = tid; i < NBUCK; i += 256)
        if (hist[i]) atomicAdd(&gbcount[i], hist[i]);
}

// ---------------- bucket scan ----------------
__global__ __launch_bounds__(1024) void bscan_kernel(const int* __restrict__ gbcount,
                                                     int* __restrict__ gbstart,
                                                     int* __restrict__ gbcursor,
                                                     int* __restrict__ rowstart) {
    __shared__ int s[1024];
    const int tid = threadIdx.x;
    int v = (tid < NBUCK) ? gbcount[tid] : 0;
    s[tid] = v;
    __syncthreads();
    for (int off = 1; off < 1024; off <<= 1) {
        int t = (tid >= off) ? s[tid - off] : 0;
        __syncthreads();
        s[tid] += t;
        __syncthreads();
    }
    if (tid < NBUCK) {
        int e = s[tid] - v;
        gbstart[tid] = e;
        gbcursor[tid] = e;
    }
    if (tid == 0) { gbstart[NBUCK] = EE; rowstart[NN] = EE; }
}

// ---------------- P2: bin edges into buckets (packed src | dstlow<<17) ----------------
__global__ __launch_bounds__(256) void p2_bin_kernel(const void* __restrict__ eiv,
                                                     const int* __restrict__ flag,
                                                     int* __restrict__ gbcursor,
                                                     unsigned int* __restrict__ packed) {
    __shared__ int hist[NBUCK];
    __shared__ int basep[NBUCK];
    const int tid = threadIdx.x;
    const int f = *flag;
    for (int i = tid; i < NBUCK; i += 256) hist[i] = 0;
    __syncthreads();
    int beg = blockIdx.x * CHUNK, end = min(beg + CHUNK, EE);
    for (int e = beg + tid; e < end; e += 256)
        atomicAdd(&hist[edge_dst(eiv, f, e) >> BSHIFT], 1);
    __syncthreads();
    for (int i = tid; i < NBUCK; i += 256) {
        int c = hist[i];
        if (c) basep[i] = atomicAdd(&gbcursor[i], c);
        hist[i] = 0;
    }
    __syncthreads();
    for (int e = beg + tid; e < end; e += 256) {
        int s = edge_src(eiv, f, e);
        int d = edge_dst(eiv, f, e);
        int b = d >> BSHIFT;
        int r = atomicAdd(&hist[b], 1);
        packed[basep[b] + r] = (unsigned int)s | ((unsigned int)(d & 127) << 17);
    }
}

// ---------------- P3: per-bucket counting sort -> rowstart + eidx ----------------
__global__ __launch_bounds__(256) void p3_sort_kernel(const unsigned int* __restrict__ packed,
                                                      const int* __restrict__ gbstart,
                                                      int* __restrict__ rowstart,
                                                      int* __restrict__ eidx) {
    __shared__ int hist[128];
    __shared__ int excl[128];
    __shared__ int s[128];
    const int tid = threadIdx.x;
    const int b = blockIdx.x;
    const int bstart = gbstart[b], bend = gbstart[b + 1];
    if (tid < 128) hist[tid] = 0;
    __syncthreads();
    for (int e = bstart + tid; e < bend; e += 256)
        atomicAdd(&hist[packed[e] >> 17], 1);
    __syncthreads();
    int v = (tid < 128) ? hist[tid] : 0;
    if (tid < 128) s[tid] = v;
    __syncthreads();
    for (int off = 1; off < 128; off <<= 1) {
        int t = (tid < 128 && tid >= off) ? s[tid - off] : 0;
        __syncthreads();
        if (tid < 128) s[tid] += t;
        __syncthreads();
    }
    if (tid < 128) {
        excl[tid] = s[tid] - v;
        hist[tid] = 0;
        int node = b * 128 + tid;
        if (node < NN) rowstart[node] = bstart + excl[tid];
    }
    __syncthreads();
    for (int e = bstart + tid; e < bend; e += 256) {
        unsigned int p = packed[e];
        int dl = p >> 17;
        int r = atomicAdd(&hist[dl], 1);
        eidx[bstart + excl[dl] + r] = (int)(p & 0x1FFFFu);
    }
}

// ---------------- x f32 -> bf16 ----------------
__global__ __launch_bounds__(256) void cvt_kernel(const float* __restrict__ x,
                                                  unsigned short* __restrict__ xb, int n8) {
    int i = blockIdx.x * 256 + threadIdx.x;
    if (i >= n8) return;
    float4 a = ((const float4*)x)[i * 2];
    float4 b = ((const float4*)x)[i * 2 + 1];
    uint4 o;
    o.x = pack2(a.x, a.y); o.y = pack2(a.z, a.w);
    o.z = pack2(b.x, b.y); o.w = pack2(b.z, b.w);
    ((uint4*)xb)[i] = o;
}

// ---------------- pull gather (bf16) ----------------
template <int FDIM, int NPB>
__global__ __launch_bounds__(256) void gather_bf_kernel(const unsigned short* __restrict__ xin,
                                                        const int* __restrict__ rowstart,
                                                        const int* __restrict__ eidx,
                                                        unsigned short* __restrict__ agg) {
    constexpr int LPN = FDIM / 2;
    int node = blockIdx.x * NPB + threadIdx.x / LPN;
    int lane = threadIdx.x % LPN;
    if (node >= NN) return;
    int beg = rowstart[node], end = rowstart[node + 1];
    unsigned int self = *(const unsigned int*)(xin + (size_t)node * FDIM + lane * 2);
    float ax = b2f((unsigned short)(self & 0xffff));
    float ay = b2f((unsigned short)(self >> 16));
    int j = beg;
    for (; j + 1 < end; j += 2) {
        int s0 = eidx[j], s1 = eidx[j + 1];
        unsigned int v0 = *(const unsigned int*)(xin + (size_t)s0 * FDIM + lane * 2);
        unsigned int v1 = *(const unsigned int*)(xin + (size_t)s1 * FDIM + lane * 2);
        ax += b2f((unsigned short)(v0 & 0xffff)) + b2f((unsigned short)(v1 & 0xffff));
        ay += b2f((unsigned short)(v0 >> 16)) + b2f((unsigned short)(v1 >> 16));
    }
    if (j < end) {
        unsigned int v0 = *(const unsigned int*)(xin + (size_t)eidx[j] * FDIM + lane * 2);
        ax += b2f((unsigned short)(v0 & 0xffff));
        ay += b2f((unsigned short)(v0 >> 16));
    }
    *(unsigned int*)(agg + (size_t)node * FDIM + lane * 2) = pack2(ax, ay);
}

// ---------------- MFMA linear layer ----------------
template <int KIN, int MODE>
__global__ __launch_bounds__(256) void lin_kernel(const unsigned short* __restrict__ in,
                                                  const float* __restrict__ W,
                                                  const float* __restrict__ bias,
                                                  unsigned short* __restrict__ out,
                                                  float* __restrict__ bnsum,
                                                  float* __restrict__ bnsq) {
    constexpr int KLD = KIN + 8;
    constexpr int CH = KIN / 8;
    __shared__ __attribute__((aligned(16))) unsigned short smem[MBLK * KLD + 128 * KLD];
    __shared__ float sSt[256];
    unsigned short* sA = smem;
    unsigned short* sW = smem + MBLK * KLD;
    unsigned short* sO = smem;

    const int tid = threadIdx.x;
    const int wave = tid >> 6, lane = tid & 63;
    const int quad = lane >> 4, l16 = lane & 15;
    const long long row0 = (long long)blockIdx.x * MBLK;

    if (MODE == 1) sSt[tid] = 0.f;

    for (int i = tid; i < KIN * 128; i += 256) {
        int k = i >> 7, n = i & 127;
        sW[n * KLD + k] = f2bf(W[i]);
    }
    for (int i = tid; i < MBLK * CH; i += 256) {
        int r = i / CH, c = i % CH;
        uint4 v = {0u, 0u, 0u, 0u};
        if (row0 + r < NN) v = *(const uint4*)(in + (row0 + r) * KIN + c * 8);
        *(uint4*)(sA + r * KLD + c * 8) = v;
    }
    __syncthreads();

    f32x4 acc[2][8];
#pragma unroll
    for (int t = 0; t < 2; t++)
#pragma unroll
        for (int n = 0; n < 8; n++) acc[t][n] = 0.f;

#pragma unroll
    for (int ks = 0; ks < KIN / 32; ks++) {
        bf16x8 a0 = *(const bf16x8*)(sA + (wave * 32 + l16) * KLD + ks * 32 + quad * 8);
        bf16x8 a1 = *(const bf16x8*)(sA + (wave * 32 + 16 + l16) * KLD + ks * 32 + quad * 8);
#pragma unroll
        for (int nt = 0; nt < 8; nt++) {
            bf16x8 b = *(const bf16x8*)(sW + (nt * 16 + l16) * KLD + ks * 32 + quad * 8);
            acc[0][nt] = __builtin_amdgcn_mfma_f32_16x16x32_bf16(a0, b, acc[0][nt], 0, 0, 0);
            acc[1][nt] = __builtin_amdgcn_mfma_f32_16x16x32_bf16(a1, b, acc[1][nt], 0, 0, 0);
        }
    }
    __syncthreads();

#pragma unroll
    for (int nt = 0; nt < 8; nt++) {
        const int col = nt * 16 + l16;
        const float bcol = bias[col];
        float ls = 0.f, lq = 0.f;
#pragma unroll
        for (int t = 0; t < 2; t++) {
#pragma unroll
            for (int r = 0; r < 4; r++) {
                int rl = wave * 32 + t * 16 + quad * 4 + r;
                float v = acc[t][nt][r] + bcol;
                if (MODE == 0) v = fmaxf(v, 0.f);
                if (MODE == 1 && row0 + rl < NN) { ls += v; lq += v * v; }
                sO[rl * 136 + col] = f2bf(v);
            }
        }
        if (MODE == 1) {
            ls += __shfl_down(ls, 32); ls += __shfl_down(ls, 16);
            lq += __shfl_down(lq, 32); lq += __shfl_down(lq, 16);
            if (lane < 16) { atomicAdd(&sSt[col], ls); atomicAdd(&sSt[128 + col], lq); }
        }
    }
    __syncthreads();

    for (int i = tid; i < MBLK * 16; i += 256) {
        int r = i >> 4, c = i & 15;
        if (row0 + r < NN)
            *(uint4*)(out + (row0 + r) * 128 + c * 8) = *(const uint4*)(sO + r * 136 + c * 8);
    }
    if (MODE == 1) {
        if (tid < 128) atomicAdd(&bnsum[tid], sSt[tid]);
        else if (tid < 256) atomicAdd(&bnsq[tid - 128], sSt[tid]);
    }
}

// ---------------- classifier head ----------------
__global__ __launch_bounds__(256) void lin_cls_kernel(const unsigned short* __restrict__ in,
                                                      const float* __restrict__ W2,
                                                      const float* __restrict__ b2,
                                                      float* __restrict__ cls) {
    constexpr int KLD = 136;
    __shared__ __attribute__((aligned(16))) unsigned short smem[MBLK * KLD + 16 * KLD];
    unsigned short* sA = smem;
    unsigned short* sW = smem + MBLK * KLD;
    float* sOf = (float*)smem;

    const int tid = threadIdx.x;
    const int wave = tid >> 6, lane = tid & 63;
    const int quad = lane >> 4, l16 = lane & 15;
    const long long row0 = (long long)blockIdx.x * MBLK;

    for (int i = tid; i < 16 * 128; i += 256) {
        int n = i & 15, k = i >> 4;
        sW[n * KLD + k] = (n < CC) ? f2bf(W2[k * CC + n]) : (unsigned short)0;
    }
    for (int i = tid; i < MBLK * 16; i += 256) {
        int r = i >> 4, c = i & 15;
        uint4 v = {0u, 0u, 0u, 0u};
        if (row0 + r < NN) v = *(const uint4*)(in + (row0 + r) * 128 + c * 8);
        *(uint4*)(sA + r * KLD + c * 8) = v;
    }
    __syncthreads();

    f32x4 acc[2];
    acc[0] = 0.f; acc[1] = 0.f;
#pragma unroll
    for (int ks = 0; ks < 4; ks++) {
        bf16x8 a0 = *(const bf16x8*)(sA + (wave * 32 + l16) * KLD + ks * 32 + quad * 8);
        bf16x8 a1 = *(const bf16x8*)(sA + (wave * 32 + 16 + l16) * KLD + ks * 32 + quad * 8);
        bf16x8 b = *(const bf16x8*)(sW + l16 * KLD + ks * 32 + quad * 8);
        acc[0] = __builtin_amdgcn_mfma_f32_16x16x32_bf16(a0, b, acc[0], 0, 0, 0);
        acc[1] = __builtin_amdgcn_mfma_f32_16x16x32_bf16(a1, b, acc[1], 0, 0, 0);
    }
    __syncthreads();

    if (l16 < CC) {
        const float bc = b2[l16];
#pragma unroll
        for (int t = 0; t < 2; t++)
#pragma unroll
            for (int r = 0; r < 4; r++) {
                int rl = wave * 32 + t * 16 + quad * 4 + r;
                sOf[rl * CC + l16] = acc[t][r] + bc;
            }
    }
    __syncthreads();
    for (int i = tid; i < MBLK * CC; i += 256) {
        long long gi = row0 * CC + i;
        if (gi < (long long)NN * CC) cls[gi] = sOf[i];
    }
}

// ---------------- BN finalize ----------------
__global__ void bn_finalize_kernel(const float* __restrict__ sum, const float* __restrict__ sq,
                                   const float* __restrict__ g, const float* __restrict__ b,
                                   float* __restrict__ a1, float* __restrict__ a0) {
    int c = threadIdx.x;
    if (c < HH) {
        float mean = sum[c] * (1.0f / NN);
        float var = sq[c] * (1.0f / NN) - mean * mean;
        float s = g[c] * rsqrtf(var + BN_EPS);
        a1[c] = s;
        a0[c] = b[c] - mean * s;
    }
}

// ---------------- BN apply + relu (bf16 -> bf16) ----------------
__global__ __launch_bounds__(256) void bn_apply_kernel(const unsigned short* __restrict__ h,
                                                       const float* __restrict__ a1,
                                                       const float* __restrict__ a0,
                                                       unsigned short* __restrict__ hbn, int n8) {
    int i = blockIdx.x * 256 + threadIdx.x;
    if (i >= n8) return;
    int c0 = (i & 15) * 8;
    uint4 hv = ((const uint4*)h)[i];
    const unsigned int* w = (const unsigned int*)&hv;
    uint4 o;
    unsigned int* ow = (unsigned int*)&o;
#pragma unroll
    for (int p = 0; p < 4; p++) {
        float v0 = b2f((unsigned short)(w[p] & 0xffff));
        float v1 = b2f((unsigned short)(w[p] >> 16));
        int c = c0 + p * 2;
        v0 = fmaxf(fmaf(v0, a1[c], a0[c]), 0.f);
        v1 = fmaxf(fmaf(v1, a1[c + 1], a0[c + 1]), 0.f);
        ow[p] = pack2(v0, v1);
    }
    ((uint4*)hbn)[i] = o;
}

// ---------------- latent: bn2+relu -> f32 out + bf16 copy ----------------
__global__ __launch_bounds__(256) void latent_kernel(const unsigned short* __restrict__ h2,
                                                     const float* __restrict__ a1,
                                                     const float* __restrict__ a0,
                                                     float* __restrict__ latent,
                                                     unsigned short* __restrict__ latb, int n8) {
    int i = blockIdx.x * 256 + threadIdx.x;
    if (i >= n8) return;
    int c0 = (i & 15) * 8;
    uint4 hv = ((const uint4*)h2)[i];
    const unsigned int* w = (const unsigned int*)&hv;
    float vs[8];
#pragma unroll
    for (int p = 0; p < 4; p++) {
        int c = c0 + p * 2;
        vs[p * 2]     = fmaxf(fmaf(b2f((unsigned short)(w[p] & 0xffff)), a1[c], a0[c]), 0.f);
        vs[p * 2 + 1] = fmaxf(fmaf(b2f((unsigned short)(w[p] >> 16)), a1[c + 1], a0[c + 1]), 0.f);
    }
    float4 f0 = {vs[0], vs[1], vs[2], vs[3]};
    float4 f1 = {vs[4], vs[5], vs[6], vs[7]};
    ((float4*)latent)[i * 2] = f0;
    ((float4*)latent)[i * 2 + 1] = f1;
    uint4 o;
    o.x = pack2(vs[0], vs[1]); o.y = pack2(vs[2], vs[3]);
    o.z = pack2(vs[4], vs[5]); o.w = pack2(vs[6], vs[7]);
    ((uint4*)latb)[i] = o;
}

extern "C" void kernel_launch(void* const* d_in, const int* in_sizes, int n_in,
                              void* d_out, int out_size, void* d_ws, size_t ws_size,
                              hipStream_t stream) {
    const float* x   = (const float*)d_in[0];
    const void* ei   = d_in[1];
    const float* w1a = (const float*)d_in[2];
    const float* b1a = (const float*)d_in[3];
    const float* w1b = (const float*)d_in[4];
    const float* b1b = (const float*)d_in[5];
    const float* w2a = (const float*)d_in[6];
    const float* b2a = (const float*)d_in[7];
    const float* w2b = (const float*)d_in[8];
    const float* b2b = (const float*)d_in[9];
    const float* bn1g = (const float*)d_in[10];
    const float* bn1b = (const float*)d_in[11];
    const float* bn2g = (const float*)d_in[12];
    const float* bn2b = (const float*)d_in[13];
    const float* mw1 = (const float*)d_in[14];
    const float* mb1 = (const float*)d_in[15];
    const float* mw2 = (const float*)d_in[16];
    const float* mb2 = (const float*)d_in[17];
    float* out = (float*)d_out;

    char* w = (char*)d_ws;
    unsigned short* agg1 = (unsigned short*)w;  w += (size_t)NN * FF * 2;
    unsigned short* t1   = (unsigned short*)w;  w += (size_t)NN * HH * 2;
    unsigned short* h    = (unsigned short*)w;  w += (size_t)NN * HH * 2;
    unsigned short* hbn  = (unsigned short*)w;  w += (size_t)NN * HH * 2;
    unsigned short* agg2 = (unsigned short*)w;  w += (size_t)NN * HH * 2;
    unsigned short* xb   = (unsigned short*)w;  w += (size_t)NN * FF * 2;
    float* stats = (float*)w;                   w += 1024 * 4;
    int* eidx = (int*)w;                        w += (size_t)EE * 4;
    unsigned int* packed = (unsigned int*)w;    w += (size_t)EE * 4;
    int* rowstart = (int*)w;                    w += (NN + 2) * 4;
    int* flag = (int*)w;                        w += 16;
    int* gbcount = (int*)w;                     w += (NBUCK + 2) * 4;
    int* gbstart = (int*)w;                     w += (NBUCK + 2) * 4;
    int* gbcursor = (int*)w;                    w += (NBUCK + 2) * 4;

    hipMemsetAsync(stats, 0, 512 * sizeof(float), stream);
    hipMemsetAsync(gbcount, 0, NBUCK * sizeof(int), stream);
    detect_kernel<<<1, 64, 0, stream>>>((const unsigned int*)ei, flag);

    // CSR via bucket sort
    p1_hist_kernel<<<NB_CH, 256, 0, stream>>>(ei, flag, gbcount);
    bscan_kernel<<<1, 1024, 0, stream>>>(gbcount, gbstart, gbcursor, rowstart);
    p2_bin_kernel<<<NB_CH, 256, 0, stream>>>(ei, flag, gbcursor, packed);
    p3_sort_kernel<<<NBUCK, 256, 0, stream>>>(packed, gbstart, rowstart, eidx);

    // conv1
    cvt_kernel<<<(NN * FF / 8 + 255) / 256, 256, 0, stream>>>(x, xb, NN * FF / 8);
    gather_bf_kernel<FF, 8><<<(NN + 7) / 8, 256, 0, stream>>>(xb, rowstart, eidx, agg1);
    lin_kernel<FF, 0><<<NBLK_LIN, 256, 0, stream>>>(agg1, w1a, b1a, t1, nullptr, nullptr);
    lin_kernel<HH, 1><<<NBLK_LIN, 256, 0, stream>>>(t1, w1b, b1b, h, stats, stats + 128);
    bn_finalize_kernel<<<1, 128, 0, stream>>>(stats, stats + 128, bn1g, bn1b, stats + 512, stats + 640);
    bn_apply_kernel<<<(NN * HH / 8 + 255) / 256, 256, 0, stream>>>(h, stats + 512, stats + 640, hbn, NN * HH / 8);

    // conv2
    gather_bf_kernel<HH, 4><<<(NN + 3) / 4, 256, 0, stream>>>(hbn, rowstart, eidx, agg2);
    lin_kernel<HH, 0><<<NBLK_LIN, 256, 0, stream>>>(agg2, w2a, b2a, t1, nullptr, nullptr);
    lin_kernel<HH, 1><<<NBLK_LIN, 256, 0, stream>>>(t1, w2b, b2b, h, stats + 256, stats + 384);
    bn_finalize_kernel<<<1, 128, 0, stream>>>(stats + 256, stats + 384, bn2g, bn2b, stats + 768, stats + 896);

    // latent + classifier
    latent_kernel<<<(NN * HH / 8 + 255) / 256, 256, 0, stream>>>(h, stats + 768, stats + 896,
                                                                 out, hbn, NN * HH / 8);
    lin_kernel<HH, 0><<<NBLK_LIN, 256, 0, stream>>>(hbn, mw1, mb1, t1, nullptr, nullptr);
    lin_cls_kernel<<<NBLK_LIN, 256, 0, stream>>>(t1, mw2, mb2, out + (size_t)NN * HH);
}

// Round 5
// 450.016 us; speedup vs baseline: 10.8365x; 1.2302x over previous
//
#include <hip/hip_runtime.h>
#include <cstdint>

// GIN model: N=100000, F=64, H=128, C=10, E=1600000.
// R5: fuse dense tail. mlp = GEMM1(relu)->regs->LDS->GEMM2(+BN stats) in one kernel;
// BN1-apply folded into gather2; final = BN2+latent+classifier in one kernel.
// 21 dispatches -> 15; removes ~200 MB of intermediate global traffic.

#define NN 100000
#define FF 64
#define HH 128
#define CC 10
#define EE 1600000
#define BN_EPS 1e-5f
#define MBLK 128
#define NBLK_LIN ((NN + MBLK - 1) / MBLK)  // 782
#define BSHIFT 7
#define NBUCK ((NN + 127) / 128)           // 782
#define CHUNK 16384
#define NB_CH ((EE + CHUNK - 1) / CHUNK)   // 98

typedef __attribute__((ext_vector_type(8))) short bf16x8;
typedef __attribute__((ext_vector_type(4))) float f32x4;

__device__ inline unsigned short f2bf(float f) {
    unsigned int u = __float_as_uint(f);
    unsigned int r = (u + 0x7fffu + ((u >> 16) & 1u)) >> 16;
    return (unsigned short)r;
}
__device__ inline float b2f(unsigned short h) {
    return __uint_as_float(((unsigned int)h) << 16);
}
__device__ inline unsigned int pack2(float a, float b) {
    return (unsigned int)f2bf(a) | ((unsigned int)f2bf(b) << 16);
}

// ---------------- edge dtype detection ----------------
__global__ void detect_kernel(const unsigned int* __restrict__ ei, int* __restrict__ flag) {
    if (threadIdx.x == 0) {
        bool i64 = (ei[1] == 0u) && (ei[3] == 0u) && (ei[5] == 0u) && (ei[7] == 0u);
        *flag = i64 ? 1 : 0;
    }
}

__device__ inline int edge_dst(const void* eiv, int f, int e) {
    return f ? (int)((const long long*)eiv)[EE + e] : ((const int*)eiv)[EE + e];
}
__device__ inline int edge_src(const void* eiv, int f, int e) {
    return f ? (int)((const long long*)eiv)[e] : ((const int*)eiv)[e];
}

// ---------------- P1: coarse bucket histogram ----------------
__global__ __launch_bounds__(256) void p1_hist_kernel(const void* __restrict__ eiv,
                                                      const int* __restrict__ flag,
                                                      int* __restrict__ gbcount) {
    __shared__ int hist[NBUCK];
    const int tid = threadIdx.x;
    const int f = *flag;
    for (int i = tid; i < NBUCK; i += 256) hist[i] = 0;
    __syncthreads();
    int beg = blockIdx.x * CHUNK, end = min(beg + CHUNK, EE);
    for (int e = beg + tid; e < end; e += 256)
        atomicAdd(&hist[edge_dst(eiv, f, e) >> BSHIFT], 1);
    __syncthreads();
    for (int i = tid; i < NBUCK; i += 256)
        if (hist[i]) atomicAdd(&gbcount[i], hist[i]);
}

// ---------------- bucket scan ----------------
__global__ __launch_bounds__(1024) void bscan_kernel(const int* __restrict__ gbcount,
                                                     int* __restrict__ gbstart,
                                                     int* __restrict__ gbcursor,
                                                     int* __restrict__ rowstart) {
    __shared__ int s[1024];
    const int tid = threadIdx.x;
    int v = (tid < NBUCK) ? gbcount[tid] : 0;
    s[tid] = v;
    __syncthreads();
    for (int off = 1; off < 1024; off <<= 1) {
        int t = (tid >= off) ? s[tid - off] : 0;
        __syncthreads();
        s[tid] += t;
        __syncthreads();
    }
    if (tid < NBUCK) {
        int e = s[tid] - v;
        gbstart[tid] = e;
        gbcursor[tid] = e;
    }
    if (tid == 0) { gbstart[NBUCK] = EE; rowstart[NN] = EE; }
}

// ---------------- P2: bin edges (packed src | dstlow<<17) ----------------
__global__ __launch_bounds__(256) void p2_bin_kernel(const void* __restrict__ eiv,
                                                     const int* __restrict__ flag,
                                                     int* __restrict__ gbcursor,
                                                     unsigned int* __restrict__ packed) {
    __shared__ int hist[NBUCK];
    __shared__ int basep[NBUCK];
    const int tid = threadIdx.x;
    const int f = *flag;
    for (int i = tid; i < NBUCK; i += 256) hist[i] = 0;
    __syncthreads();
    int beg = blockIdx.x * CHUNK, end = min(beg + CHUNK, EE);
    for (int e = beg + tid; e < end; e += 256)
        atomicAdd(&hist[edge_dst(eiv, f, e) >> BSHIFT], 1);
    __syncthreads();
    for (int i = tid; i < NBUCK; i += 256) {
        int c = hist[i];
        if (c) basep[i] = atomicAdd(&gbcursor[i], c);
        hist[i] = 0;
    }
    __syncthreads();
    for (int e = beg + tid; e < end; e += 256) {
        int s = edge_src(eiv, f, e);
        int d = edge_dst(eiv, f, e);
        int b = d >> BSHIFT;
        int r = atomicAdd(&hist[b], 1);
        packed[basep[b] + r] = (unsigned int)s | ((unsigned int)(d & 127) << 17);
    }
}

// ---------------- P3: per-bucket counting sort -> rowstart + eidx ----------------
__global__ __launch_bounds__(256) void p3_sort_kernel(const unsigned int* __restrict__ packed,
                                                      const int* __restrict__ gbstart,
                                                      int* __restrict__ rowstart,
                                                      int* __restrict__ eidx) {
    __shared__ int hist[128];
    __shared__ int excl[128];
    __shared__ int s[128];
    const int tid = threadIdx.x;
    const int b = blockIdx.x;
    const int bstart = gbstart[b], bend = gbstart[b + 1];
    if (tid < 128) hist[tid] = 0;
    __syncthreads();
    for (int e = bstart + tid; e < bend; e += 256)
        atomicAdd(&hist[packed[e] >> 17], 1);
    __syncthreads();
    int v = (tid < 128) ? hist[tid] : 0;
    if (tid < 128) s[tid] = v;
    __syncthreads();
    for (int off = 1; off < 128; off <<= 1) {
        int t = (tid < 128 && tid >= off) ? s[tid - off] : 0;
        __syncthreads();
        if (tid < 128) s[tid] += t;
        __syncthreads();
    }
    if (tid < 128) {
        excl[tid] = s[tid] - v;
        hist[tid] = 0;
        int node = b * 128 + tid;
        if (node < NN) rowstart[node] = bstart + excl[tid];
    }
    __syncthreads();
    for (int e = bstart + tid; e < bend; e += 256) {
        unsigned int p = packed[e];
        int dl = p >> 17;
        int r = atomicAdd(&hist[dl], 1);
        eidx[bstart + excl[dl] + r] = (int)(p & 0x1FFFFu);
    }
}

// ---------------- x f32 -> bf16 ----------------
__global__ __launch_bounds__(256) void cvt_kernel(const float* __restrict__ x,
                                                  unsigned short* __restrict__ xb, int n8) {
    int i = blockIdx.x * 256 + threadIdx.x;
    if (i >= n8) return;
    float4 a = ((const float4*)x)[i * 2];
    float4 b = ((const float4*)x)[i * 2 + 1];
    uint4 o;
    o.x = pack2(a.x, a.y); o.y = pack2(a.z, a.w);
    o.z = pack2(b.x, b.y); o.w = pack2(b.z, b.w);
    ((uint4*)xb)[i] = o;
}

// ---------------- pull gather, plain (conv1) ----------------
template <int FDIM, int NPB>
__global__ __launch_bounds__(256) void gather_bf_kernel(const unsigned short* __restrict__ xin,
                                                        const int* __restrict__ rowstart,
                                                        const int* __restrict__ eidx,
                                                        unsigned short* __restrict__ agg) {
    constexpr int LPN = FDIM / 2;
    int node = blockIdx.x * NPB + threadIdx.x / LPN;
    int lane = threadIdx.x % LPN;
    if (node >= NN) return;
    int beg = rowstart[node], end = rowstart[node + 1];
    unsigned int self = *(const unsigned int*)(xin + (size_t)node * FDIM + lane * 2);
    float ax = b2f((unsigned short)(self & 0xffff));
    float ay = b2f((unsigned short)(self >> 16));
    int j = beg;
    for (; j + 3 < end; j += 4) {
        int s0 = eidx[j], s1 = eidx[j + 1], s2 = eidx[j + 2], s3 = eidx[j + 3];
        unsigned int v0 = *(const unsigned int*)(xin + (size_t)s0 * FDIM + lane * 2);
        unsigned int v1 = *(const unsigned int*)(xin + (size_t)s1 * FDIM + lane * 2);
        unsigned int v2 = *(const unsigned int*)(xin + (size_t)s2 * FDIM + lane * 2);
        unsigned int v3 = *(const unsigned int*)(xin + (size_t)s3 * FDIM + lane * 2);
        ax += b2f((unsigned short)(v0 & 0xffff)) + b2f((unsigned short)(v1 & 0xffff))
            + b2f((unsigned short)(v2 & 0xffff)) + b2f((unsigned short)(v3 & 0xffff));
        ay += b2f((unsigned short)(v0 >> 16)) + b2f((unsigned short)(v1 >> 16))
            + b2f((unsigned short)(v2 >> 16)) + b2f((unsigned short)(v3 >> 16));
    }
    for (; j < end; j++) {
        unsigned int v0 = *(const unsigned int*)(xin + (size_t)eidx[j] * FDIM + lane * 2);
        ax += b2f((unsigned short)(v0 & 0xffff));
        ay += b2f((unsigned short)(v0 >> 16));
    }
    *(unsigned int*)(agg + (size_t)node * FDIM + lane * 2) = pack2(ax, ay);
}

// ---------------- pull gather with fused BN1+relu on source (conv2) ----------------
// agg[i] = bnrelu(h[i]) + sum_j bnrelu(h[j])
template <int FDIM, int NPB>
__global__ __launch_bounds__(256) void gather_bn_kernel(const unsigned short* __restrict__ h,
                                                        const int* __restrict__ rowstart,
                                                        const int* __restrict__ eidx,
                                                        const float* __restrict__ a1,
                                                        const float* __restrict__ a0,
                                                        unsigned short* __restrict__ agg) {
    constexpr int LPN = FDIM / 2;
    int node = blockIdx.x * NPB + threadIdx.x / LPN;
    int lane = threadIdx.x % LPN;
    if (node >= NN) return;
    const int c = lane * 2;
    const float s0c = a1[c], s1c = a1[c + 1], o0c = a0[c], o1c = a0[c + 1];
    int beg = rowstart[node], end = rowstart[node + 1];
    unsigned int self = *(const unsigned int*)(h + (size_t)node * FDIM + lane * 2);
    float ax = fmaxf(fmaf(b2f((unsigned short)(self & 0xffff)), s0c, o0c), 0.f);
    float ay = fmaxf(fmaf(b2f((unsigned short)(self >> 16)), s1c, o1c), 0.f);
    int j = beg;
    for (; j + 3 < end; j += 4) {
        int i0 = eidx[j], i1 = eidx[j + 1], i2 = eidx[j + 2], i3 = eidx[j + 3];
        unsigned int v0 = *(const unsigned int*)(h + (size_t)i0 * FDIM + lane * 2);
        unsigned int v1 = *(const unsigned int*)(h + (size_t)i1 * FDIM + lane * 2);
        unsigned int v2 = *(const unsigned int*)(h + (size_t)i2 * FDIM + lane * 2);
        unsigned int v3 = *(const unsigned int*)(h + (size_t)i3 * FDIM + lane * 2);
        ax += fmaxf(fmaf(b2f((unsigned short)(v0 & 0xffff)), s0c, o0c), 0.f)
            + fmaxf(fmaf(b2f((unsigned short)(v1 & 0xffff)), s0c, o0c), 0.f)
            + fmaxf(fmaf(b2f((unsigned short)(v2 & 0xffff)), s0c, o0c), 0.f)
            + fmaxf(fmaf(b2f((unsigned short)(v3 & 0xffff)), s0c, o0c), 0.f);
        ay += fmaxf(fmaf(b2f((unsigned short)(v0 >> 16)), s1c, o1c), 0.f)
            + fmaxf(fmaf(b2f((unsigned short)(v1 >> 16)), s1c, o1c), 0.f)
            + fmaxf(fmaf(b2f((unsigned short)(v2 >> 16)), s1c, o1c), 0.f)
            + fmaxf(fmaf(b2f((unsigned short)(v3 >> 16)), s1c, o1c), 0.f);
    }
    for (; j < end; j++) {
        unsigned int v0 = *(const unsigned int*)(h + (size_t)eidx[j] * FDIM + lane * 2);
        ax += fmaxf(fmaf(b2f((unsigned short)(v0 & 0xffff)), s0c, o0c), 0.f);
        ay += fmaxf(fmaf(b2f((unsigned short)(v0 >> 16)), s1c, o1c), 0.f);
    }
    *(unsigned int*)(agg + (size_t)node * FDIM + lane * 2) = pack2(ax, ay);
}

// ---------------- fused MLP: h = relu(in@Wa+ba)@Wb+bb, BN stats on h ----------------
template <int KIN>
__global__ __launch_bounds__(256) void mlp_kernel(const unsigned short* __restrict__ in,
                                                  const float* __restrict__ Wa,
                                                  const float* __restrict__ ba,
                                                  const float* __restrict__ Wb,
                                                  const float* __restrict__ bb,
                                                  unsigned short* __restrict__ out,
                                                  float* __restrict__ bnsum,
                                                  float* __restrict__ bnsq) {
    constexpr int KLDA = KIN + 8;   // A-stage stride
    constexpr int CH = KIN / 8;
    __shared__ __attribute__((aligned(16))) unsigned short sA[MBLK * 136];
    __shared__ __attribute__((aligned(16))) unsigned short sW[128 * 136];
    __shared__ float sSt[256];
    __shared__ float sB[256];       // ba | bb

    const int tid = threadIdx.x;
    const int wave = tid >> 6, lane = tid & 63;
    const int quad = lane >> 4, l16 = lane & 15;
    const long long row0 = (long long)blockIdx.x * MBLK;

    sSt[tid] = 0.f;
    if (tid < 128) sB[tid] = ba[tid];
    else sB[tid] = bb[tid - 128];

    // stage Wa^T (stride KLDA) and A tile (stride KLDA)
    for (int i = tid; i < KIN * 128; i += 256) {
        int k = i >> 7, n = i & 127;
        sW[n * KLDA + k] = f2bf(Wa[i]);
    }
    for (int i = tid; i < MBLK * CH; i += 256) {
        int r = i / CH, c = i % CH;
        uint4 v = {0u, 0u, 0u, 0u};
        if (row0 + r < NN) v = *(const uint4*)(in + (row0 + r) * KIN + c * 8);
        *(uint4*)(sA + r * KLDA + c * 8) = v;
    }
    __syncthreads();

    // GEMM1: t = relu(A @ Wa + ba), acc in regs
    f32x4 acc1[2][8];
#pragma unroll
    for (int t = 0; t < 2; t++)
#pragma unroll
        for (int n = 0; n < 8; n++) acc1[t][n] = 0.f;
#pragma unroll
    for (int ks = 0; ks < KIN / 32; ks++) {
        bf16x8 a0 = *(const bf16x8*)(sA + (wave * 32 + l16) * KLDA + ks * 32 + quad * 8);
        bf16x8 a1 = *(const bf16x8*)(sA + (wave * 32 + 16 + l16) * KLDA + ks * 32 + quad * 8);
#pragma unroll
        for (int nt = 0; nt < 8; nt++) {
            bf16x8 b = *(const bf16x8*)(sW + (nt * 16 + l16) * KLDA + ks * 32 + quad * 8);
            acc1[0][nt] = __builtin_amdgcn_mfma_f32_16x16x32_bf16(a0, b, acc1[0][nt], 0, 0, 0);
            acc1[1][nt] = __builtin_amdgcn_mfma_f32_16x16x32_bf16(a1, b, acc1[1][nt], 0, 0, 0);
        }
    }
    __syncthreads();  // all reads of sA/sW done

    // write t (stride 136) + stage Wb^T (stride 136)
#pragma unroll
    for (int nt = 0; nt < 8; nt++) {
        const int col = nt * 16 + l16;
        const float bcol = sB[col];
#pragma unroll
        for (int t = 0; t < 2; t++)
#pragma unroll
            for (int r = 0; r < 4; r++) {
                int rl = wave * 32 + t * 16 + quad * 4 + r;
                sA[rl * 136 + col] = f2bf(fmaxf(acc1[t][nt][r] + bcol, 0.f));
            }
    }
    for (int i = tid; i < 128 * 128; i += 256) {
        int k = i >> 7, n = i & 127;
        sW[n * 136 + k] = f2bf(Wb[i]);
    }
    __syncthreads();

    // GEMM2: h = t @ Wb + bb
    f32x4 acc2[2][8];
#pragma unroll
    for (int t = 0; t < 2; t++)
#pragma unroll
        for (int n = 0; n < 8; n++) acc2[t][n] = 0.f;
#pragma unroll
    for (int ks = 0; ks < 4; ks++) {
        bf16x8 a0 = *(const bf16x8*)(sA + (wave * 32 + l16) * 136 + ks * 32 + quad * 8);
        bf16x8 a1 = *(const bf16x8*)(sA + (wave * 32 + 16 + l16) * 136 + ks * 32 + quad * 8);
#pragma unroll
        for (int nt = 0; nt < 8; nt++) {
            bf16x8 b = *(const bf16x8*)(sW + (nt * 16 + l16) * 136 + ks * 32 + quad * 8);
            acc2[0][nt] = __builtin_amdgcn_mfma_f32_16x16x32_bf16(a0, b, acc2[0][nt], 0, 0, 0);
            acc2[1][nt] = __builtin_amdgcn_mfma_f32_16x16x32_bf16(a1, b, acc2[1][nt], 0, 0, 0);
        }
    }
    __syncthreads();  // t reads done; sA becomes output stage

    // epilogue: +bb, BN stats, stage out
#pragma unroll
    for (int nt = 0; nt < 8; nt++) {
        const int col = nt * 16 + l16;
        const float bcol = sB[128 + col];
        float ls = 0.f, lq = 0.f;
#pragma unroll
        for (int t = 0; t < 2; t++)
#pragma unroll
            for (int r = 0; r < 4; r++) {
                int rl = wave * 32 + t * 16 + quad * 4 + r;
                float v = acc2[t][nt][r] + bcol;
                if (row0 + rl < NN) { ls += v; lq += v * v; }
                sA[rl * 136 + col] = f2bf(v);
            }
        ls += __shfl_down(ls, 32); ls += __shfl_down(ls, 16);
        lq += __shfl_down(lq, 32); lq += __shfl_down(lq, 16);
        if (lane < 16) { atomicAdd(&sSt[col], ls); atomicAdd(&sSt[128 + col], lq); }
    }
    __syncthreads();

    for (int i = tid; i < MBLK * 16; i += 256) {
        int r = i >> 4, c = i & 15;
        if (row0 + r < NN)
            *(uint4*)(out + (row0 + r) * 128 + c * 8) = *(const uint4*)(sA + r * 136 + c * 8);
    }
    if (tid < 128) atomicAdd(&bnsum[tid], sSt[tid]);
    else atomicAdd(&bnsq[tid - 128], sSt[tid]);
}

// ---------------- BN finalize ----------------
__global__ void bn_finalize_kernel(const float* __restrict__ sum, const float* __restrict__ sq,
                                   const float* __restrict__ g, const float* __restrict__ b,
                                   float* __restrict__ a1, float* __restrict__ a0) {
    int c = threadIdx.x;
    if (c < HH) {
        float mean = sum[c] * (1.0f / NN);
        float var = sq[c] * (1.0f / NN) - mean * mean;
        float s = g[c] * rsqrtf(var + BN_EPS);
        a1[c] = s;
        a0[c] = b[c] - mean * s;
    }
}

// ---------------- final: bn2+relu -> latent f32; m=relu(lat@mw1+mb1); cls=m@mw2+mb2 ----------------
__global__ __launch_bounds__(256) void final_kernel(const unsigned short* __restrict__ h2,
                                                    const float* __restrict__ a1,
                                                    const float* __restrict__ a0,
                                                    const float* __restrict__ mw1,
                                                    const float* __restrict__ mb1,
                                                    const float* __restrict__ mw2,
                                                    const float* __restrict__ mb2,
                                                    float* __restrict__ latent,
                                                    float* __restrict__ cls) {
    __shared__ __attribute__((aligned(16))) unsigned short sA[MBLK * 136];
    __shared__ __attribute__((aligned(16))) unsigned short sW[128 * 136];
    __shared__ float sBN[256];  // a1 | a0
    __shared__ float sB1[128];

    const int tid = threadIdx.x;
    const int wave = tid >> 6, lane = tid & 63;
    const int quad = lane >> 4, l16 = lane & 15;
    const long long row0 = (long long)blockIdx.x * MBLK;

    if (tid < 128) { sBN[tid] = a1[tid]; sB1[tid] = mb1[tid]; }
    else sBN[tid] = a0[tid - 128];
    for (int i = tid; i < 128 * 128; i += 256) {
        int k = i >> 7, n = i & 127;
        sW[n * 136 + k] = f2bf(mw1[i]);
    }
    __syncthreads();

    // stage: lat = bnrelu(h2); write latent f32 + sA bf16
    for (int i = tid; i < MBLK * 16; i += 256) {
        int r = i >> 4, c = i & 15;
        bool live = (row0 + r < NN);
        uint4 hv = {0u, 0u, 0u, 0u};
        if (live) hv = *(const uint4*)(h2 + (row0 + r) * 128 + c * 8);
        const unsigned int* wv = (const unsigned int*)&hv;
        float vs[8];
#pragma unroll
        for (int p = 0; p < 4; p++) {
            int cc = c * 8 + p * 2;
            vs[p * 2]     = fmaxf(fmaf(b2f((unsigned short)(wv[p] & 0xffff)), sBN[cc], sBN[128 + cc]), 0.f);
            vs[p * 2 + 1] = fmaxf(fmaf(b2f((unsigned short)(wv[p] >> 16)), sBN[cc + 1], sBN[129 + cc]), 0.f);
        }
        if (live) {
            float4 f0 = {vs[0], vs[1], vs[2], vs[3]};
            float4 f1 = {vs[4], vs[5], vs[6], vs[7]};
            float* lp = latent + (row0 + r) * 128 + c * 8;
            *(float4*)lp = f0;
            *(float4*)(lp + 4) = f1;
        }
        uint4 o;
        o.x = pack2(vs[0], vs[1]); o.y = pack2(vs[2], vs[3]);
        o.z = pack2(vs[4], vs[5]); o.w = pack2(vs[6], vs[7]);
        *(uint4*)(sA + r * 136 + c * 8) = o;
    }
    __syncthreads();

    // GEMM1: m = relu(lat @ mw1 + mb1)
    f32x4 acc1[2][8];
#pragma unroll
    for (int t = 0; t < 2; t++)
#pragma unroll
        for (int n = 0; n < 8; n++) acc1[t][n] = 0.f;
#pragma unroll
    for (int ks = 0; ks < 4; ks++) {
        bf16x8 av0 = *(const bf16x8*)(sA + (wave * 32 + l16) * 136 + ks * 32 + quad * 8);
        bf16x8 av1 = *(const bf16x8*)(sA + (wave * 32 + 16 + l16) * 136 + ks * 32 + quad * 8);
#pragma unroll
        for (int nt = 0; nt < 8; nt++) {
            bf16x8 b = *(const bf16x8*)(sW + (nt * 16 + l16) * 136 + ks * 32 + quad * 8);
            acc1[0][nt] = __builtin_amdgcn_mfma_f32_16x16x32_bf16(av0, b, acc1[0][nt], 0, 0, 0);
            acc1[1][nt] = __builtin_amdgcn_mfma_f32_16x16x32_bf16(av1, b, acc1[1][nt], 0, 0, 0);
        }
    }
    __syncthreads();

    // write m to sA; stage mw2 (padded to 16 cols) into sW
#pragma unroll
    for (int nt = 0; nt < 8; nt++) {
        const int col = nt * 16 + l16;
        const float bcol = sB1[col];
#pragma unroll
        for (int t = 0; t < 2; t++)
#pragma unroll
            for (int r = 0; r < 4; r++) {
                int rl = wave * 32 + t * 16 + quad * 4 + r;
                sA[rl * 136 + col] = f2bf(fmaxf(acc1[t][nt][r] + bcol, 0.f));
            }
    }
    for (int i = tid; i < 16 * 128; i += 256) {
        int n = i & 15, k = i >> 4;
        sW[n * 136 + k] = (n < CC) ? f2bf(mw2[k * CC + n]) : (unsigned short)0;
    }
    __syncthreads();

    // GEMM2: cls = m @ mw2 + mb2
    f32x4 acc2[2];
    acc2[0] = 0.f; acc2[1] = 0.f;
#pragma unroll
    for (int ks = 0; ks < 4; ks++) {
        bf16x8 av0 = *(const bf16x8*)(sA + (wave * 32 + l16) * 136 + ks * 32 + quad * 8);
        bf16x8 av1 = *(const bf16x8*)(sA + (wave * 32 + 16 + l16) * 136 + ks * 32 + quad * 8);
        bf16x8 b = *(const bf16x8*)(sW + l16 * 136 + ks * 32 + quad * 8);
        acc2[0] = __builtin_amdgcn_mfma_f32_16x16x32_bf16(av0, b, acc2[0], 0, 0, 0);
        acc2[1] = __builtin_amdgcn_mfma_f32_16x16x32_bf16(av1, b, acc2[1], 0, 0, 0);
    }
    __syncthreads();

    float* sOf = (float*)sA;  // MBLK x CC staging
    if (l16 < CC) {
        const float bc = mb2[l16];
#pragma unroll
        for (int t = 0; t < 2; t++)
#pragma unroll
            for (int r = 0; r < 4; r++) {
                int rl = wave * 32 + t * 16 + quad * 4 + r;
                sOf[rl * CC + l16] = acc2[t][r] + bc;
            }
    }
    __syncthreads();
    for (int i = tid; i < MBLK * CC; i += 256) {
        long long gi = row0 * CC + i;
        if (gi < (long long)NN * CC) cls[gi] = sOf[i];
    }
}

extern "C" void kernel_launch(void* const* d_in, const int* in_sizes, int n_in,
                              void* d_out, int out_size, void* d_ws, size_t ws_size,
                              hipStream_t stream) {
    const float* x   = (const float*)d_in[0];
    const void* ei   = d_in[1];
    const float* w1a = (const float*)d_in[2];
    const float* b1a = (const float*)d_in[3];
    const float* w1b = (const float*)d_in[4];
    const float* b1b = (const float*)d_in[5];
    const float* w2a = (const float*)d_in[6];
    const float* b2a = (const float*)d_in[7];
    const float* w2b = (const float*)d_in[8];
    const float* b2b = (const float*)d_in[9];
    const float* bn1g = (const float*)d_in[10];
    const float* bn1b = (const float*)d_in[11];
    const float* bn2g = (const float*)d_in[12];
    const float* bn2b = (const float*)d_in[13];
    const float* mw1 = (const float*)d_in[14];
    const float* mb1 = (const float*)d_in[15];
    const float* mw2 = (const float*)d_in[16];
    const float* mb2 = (const float*)d_in[17];
    float* out = (float*)d_out;

    char* w = (char*)d_ws;
    unsigned short* agg1 = (unsigned short*)w;  w += (size_t)NN * FF * 2;
    unsigned short* h    = (unsigned short*)w;  w += (size_t)NN * HH * 2;   // h1 then h2
    unsigned short* agg2 = (unsigned short*)w;  w += (size_t)NN * HH * 2;
    unsigned short* xb   = (unsigned short*)w;  w += (size_t)NN * FF * 2;
    float* stats = (float*)w;                   w += 1024 * 4;
    int* eidx = (int*)w;                        w += (size_t)EE * 4;
    unsigned int* packed = (unsigned int*)w;    w += (size_t)EE * 4;
    int* rowstart = (int*)w;                    w += (NN + 2) * 4;
    int* flag = (int*)w;                        w += 16;
    int* gbcount = (int*)w;                     w += (NBUCK + 2) * 4;
    int* gbstart = (int*)w;                     w += (NBUCK + 2) * 4;
    int* gbcursor = (int*)w;                    w += (NBUCK + 2) * 4;

    hipMemsetAsync(stats, 0, 512 * sizeof(float), stream);
    hipMemsetAsync(gbcount, 0, NBUCK * sizeof(int), stream);
    detect_kernel<<<1, 64, 0, stream>>>((const unsigned int*)ei, flag);

    // CSR via bucket sort
    p1_hist_kernel<<<NB_CH, 256, 0, stream>>>(ei, flag, gbcount);
    bscan_kernel<<<1, 1024, 0, stream>>>(gbcount, gbstart, gbcursor, rowstart);
    p2_bin_kernel<<<NB_CH, 256, 0, stream>>>(ei, flag, gbcursor, packed);
    p3_sort_kernel<<<NBUCK, 256, 0, stream>>>(packed, gbstart, rowstart, eidx);

    // conv1
    cvt_kernel<<<(NN * FF / 8 + 255) / 256, 256, 0, stream>>>(x, xb, NN * FF / 8);
    gather_bf_kernel<FF, 8><<<(NN + 7) / 8, 256, 0, stream>>>(xb, rowstart, eidx, agg1);
    mlp_kernel<FF><<<NBLK_LIN, 256, 0, stream>>>(agg1, w1a, b1a, w1b, b1b, h, stats, stats + 128);
    bn_finalize_kernel<<<1, 128, 0, stream>>>(stats, stats + 128, bn1g, bn1b, stats + 512, stats + 640);

    // conv2 (BN1+relu fused into gather)
    gather_bn_kernel<HH, 4><<<(NN + 3) / 4, 256, 0, stream>>>(h, rowstart, eidx,
                                                              stats + 512, stats + 640, agg2);
    mlp_kernel<HH><<<NBLK_LIN, 256, 0, stream>>>(agg2, w2a, b2a, w2b, b2b, h, stats + 256, stats + 384);
    bn_finalize_kernel<<<1, 128, 0, stream>>>(stats + 256, stats + 384, bn2g, bn2b, stats + 768, stats + 896);

    // latent + classifier fused
    final_kernel<<<NBLK_LIN, 256, 0, stream>>>(h, stats + 768, stats + 896, mw1, mb1, mw2, mb2,
                                               out, out + (size_t)NN * HH);
}